// Round 11
// baseline (433.494 us; speedup 1.0000x reference)
//
#include <hip/hip_runtime.h>

// ---------------------------------------------------------------------------
// BiasCrossAttentionFusion on gfx950 — round 17.
//   R17 vs R16 (421.3, best): budget audit shows ~150us unexplained between
//   measured top-5 + FLOP-rate estimates -> suspect tiny-block scheduling
//   overhead (ln2: 12288 one-row blocks, transpose: 8320, ln: 4096).
//   G11: cap ~2048 blocks + grid-stride. Single change: those three kernels
//   grid-strided (transpose 2080x4, ln2 2048x6, ln 2048x2; barriers added
//   at loop ends for LDS reuse safety). Everything else byte-identical to
//   R16 (flash R10 body, GEMMs BK64+swz+T1, l2sum fused in geo).
// ---------------------------------------------------------------------------

typedef __bf16 bf16x8 __attribute__((ext_vector_type(8)));
typedef __bf16 bf16x4 __attribute__((ext_vector_type(4)));
typedef float  f32x4  __attribute__((ext_vector_type(4)));

__device__ inline f32x4 mfma16(bf16x8 a, bf16x8 b, f32x4 c) {
  return __builtin_amdgcn_mfma_f32_16x16x32_bf16(a, b, c, 0, 0, 0);
}

__device__ inline void glds16(const void* g, void* l) {
  __builtin_amdgcn_global_load_lds(
      (const __attribute__((address_space(1))) void*)g,
      (__attribute__((address_space(3))) void*)l, 16, 0, 0);
}

// swizzled LDS offset for a 64-elem bf16 row: 16B-chunk index XOR (row&7)
__device__ inline int swz(int row, int col) {
  return row * 64 + ((((col >> 3) ^ (row & 7)) << 3) | (col & 7));
}

#define DB 1024
#define DH 16
#define DHD 64
#define DP 64
#define NB 4
#define NN 1024
#define NM 2048

// ---------------- all weight transposes (f32 [K,O] -> bf16 [O,K]) ----------
// grid-stride: 2080 blocks x 4 iterations (8320 tiles)
__global__ __launch_bounds__(256) void k_transpose_all(
    const float* __restrict__ w0, const float* __restrict__ w1,
    const float* __restrict__ w2, const float* __restrict__ w3,
    const float* __restrict__ f1, const float* __restrict__ f2,
    const float* __restrict__ g0, const float* __restrict__ g1,
    __bf16* __restrict__ o0, __bf16* __restrict__ o1,
    __bf16* __restrict__ o2, __bf16* __restrict__ o3,
    __bf16* __restrict__ of1, __bf16* __restrict__ of2,
    __bf16* __restrict__ og0, __bf16* __restrict__ og1) {
  __shared__ float tile[32][33];
  int tx = threadIdx.x & 31, ty = threadIdx.x >> 5;
  for (int id = blockIdx.x; id < 8320; id += 2080) {
    const float* in;
    __bf16* out;
    int K, O, x, y;
    if (id < 4096) {
      int mi = id >> 10, r = id & 1023;
      in = mi == 0 ? w0 : mi == 1 ? w1 : mi == 2 ? w2 : w3;
      out = mi == 0 ? o0 : mi == 1 ? o1 : mi == 2 ? o2 : o3;
      K = 1024; O = 1024; x = r & 31; y = r >> 5;
    } else if (id < 6144) {
      int r = id - 4096; in = f1; out = of1; K = 1024; O = 2048; x = r & 63; y = r >> 6;
    } else if (id < 8192) {
      int r = id - 6144; in = f2; out = of2; K = 2048; O = 1024; x = r & 31; y = r >> 5;
    } else if (id < 8256) {
      int r = id - 8192; in = g0; out = og0; K = 1024; O = 64; x = r & 1; y = r >> 1;
    } else {
      int r = id - 8256; in = g1; out = og1; K = 1024; O = 64; x = r & 1; y = r >> 1;
    }
    int k0 = y * 32, o0c = x * 32;
#pragma unroll
    for (int r = ty; r < 32; r += 8)
      tile[r][tx] = in[(size_t)(k0 + r) * O + (o0c + tx)];
    __syncthreads();
#pragma unroll
    for (int r = ty; r < 32; r += 8)
      out[(size_t)(o0c + r) * K + (k0 + tx)] = (__bf16)tile[tx][r];
    __syncthreads();  // tile reused next iteration
  }
}

// ---------------- LayerNorm D=1024, bf16 out -------------------------------
__device__ inline void ln_body(const float* __restrict__ x,
                               const float* __restrict__ g,
                               const float* __restrict__ bb,
                               __bf16* __restrict__ y, size_t row) {
  int t = threadIdx.x;
  float4 v = ((const float4*)(x + row * 1024))[t];
  float s = v.x + v.y + v.z + v.w;
  float ss = v.x * v.x + v.y * v.y + v.z * v.z + v.w * v.w;
#pragma unroll
  for (int o = 32; o; o >>= 1) {
    s += __shfl_down(s, o, 64);
    ss += __shfl_down(ss, o, 64);
  }
  __shared__ float r1[4], r2[4];
  if ((t & 63) == 0) { r1[t >> 6] = s; r2[t >> 6] = ss; }
  __syncthreads();
  s = r1[0] + r1[1] + r1[2] + r1[3];
  ss = r2[0] + r2[1] + r2[2] + r2[3];
  float mu = s * (1.f / 1024.f);
  float rstd = rsqrtf(ss * (1.f / 1024.f) - mu * mu + 1e-5f);
  float4 gv = ((const float4*)g)[t];
  float4 bv = ((const float4*)bb)[t];
  __bf16* yr = y + row * 1024 + t * 4;
  yr[0] = (__bf16)((v.x - mu) * rstd * gv.x + bv.x);
  yr[1] = (__bf16)((v.y - mu) * rstd * gv.y + bv.y);
  yr[2] = (__bf16)((v.z - mu) * rstd * gv.z + bv.z);
  yr[3] = (__bf16)((v.w - mu) * rstd * gv.w + bv.w);
}

// grid-stride: 2048 blocks x 2 rows
__global__ __launch_bounds__(256) void k_layernorm(
    const float* __restrict__ x, const float* __restrict__ g,
    const float* __restrict__ bb, __bf16* __restrict__ y) {
  for (int row = blockIdx.x; row < 4096; row += 2048) {
    ln_body(x, g, bb, y, row);
    __syncthreads();  // r1/r2 reused next iteration
  }
}

// grid-stride: 2048 blocks x 6 rows (4096 q + 8192 kv)
__global__ __launch_bounds__(256) void k_layernorm2(
    const float* __restrict__ x1, const float* __restrict__ g1,
    const float* __restrict__ b1, __bf16* __restrict__ y1,
    const float* __restrict__ x2, const float* __restrict__ g2,
    const float* __restrict__ b2, __bf16* __restrict__ y2) {
  for (int row = blockIdx.x; row < 12288; row += 2048) {
    if (row < 4096) ln_body(x1, g1, b1, y1, row);
    else ln_body(x2, g2, b2, y2, row - 4096);
    __syncthreads();  // r1/r2 reused next iteration
  }
}

// ---------------- geo projections + FUSED l2 column sum-of-squares ---------
__global__ __launch_bounds__(256) void k_geo(
    const __bf16* __restrict__ qin, const __bf16* __restrict__ kvin,
    const __bf16* __restrict__ gqw, const __bf16* __restrict__ gkw,
    const float* __restrict__ gqb, const float* __restrict__ gkb,
    __bf16* __restrict__ geoq, __bf16* __restrict__ geok,
    float* __restrict__ sums) {
  const int blk = blockIdx.x;
  const bool isq = blk < 128;
  const __bf16* A = isq ? qin : kvin;
  const __bf16* Bt = isq ? gqw : gkw;
  const float* bias = isq ? gqb : gkb;
  __bf16* C = isq ? geoq : geok;
  const int row0 = (isq ? blk : blk - 128) * 32;
  __shared__ __align__(16) __bf16 As[32][72], Bs[64][72];
  __shared__ float ls[64];
  const int t = threadIdx.x, lane = t & 63, w = t >> 6;
  const int quad = lane >> 4, l15 = lane & 15;
  const int wr = w >> 1, wc = w & 1;
  const int sr = t >> 3, skc = (t & 7) * 8;
  const __bf16* aP = A + (size_t)(row0 + sr) * 1024 + skc;
  const __bf16* bP0 = Bt + (size_t)sr * 1024 + skc;
  const __bf16* bP1 = Bt + (size_t)(sr + 32) * 1024 + skc;
  bf16x8 av = *(const bf16x8*)aP;
  bf16x8 bv0 = *(const bf16x8*)bP0;
  bf16x8 bv1 = *(const bf16x8*)bP1;
  f32x4 acc[2] = {};
  for (int k0 = 0; k0 < 1024; k0 += 64) {
    __syncthreads();
    *(bf16x8*)&As[sr][skc] = av;
    *(bf16x8*)&Bs[sr][skc] = bv0;
    *(bf16x8*)&Bs[sr + 32][skc] = bv1;
    __syncthreads();
    if (k0 + 64 < 1024) {
      av = *(const bf16x8*)(aP + k0 + 64);
      bv0 = *(const bf16x8*)(bP0 + k0 + 64);
      bv1 = *(const bf16x8*)(bP1 + k0 + 64);
    }
#pragma unroll
    for (int ks = 0; ks < 2; ks++) {
      bf16x8 af = *(const bf16x8*)&As[wr * 16 + l15][ks * 32 + quad * 8];
#pragma unroll
      for (int ct = 0; ct < 2; ct++) {
        bf16x8 bfr = *(const bf16x8*)&Bs[wc * 32 + ct * 16 + l15][ks * 32 + quad * 8];
        acc[ct] = mfma16(af, bfr, acc[ct]);
      }
    }
  }
  if (t < 64) ls[t] = 0.f;
  __syncthreads();
  float sq[2] = {0.f, 0.f};
#pragma unroll
  for (int ct = 0; ct < 2; ct++) {
    int col = wc * 32 + ct * 16 + l15;
    float bc = bias[col];
#pragma unroll
    for (int i = 0; i < 4; i++) {
      int row = row0 + wr * 16 + quad * 4 + i;
      __bf16 hv = (__bf16)(acc[ct][i] + bc);
      C[(size_t)row * 64 + col] = hv;
      float fv = (float)hv;
      sq[ct] += fv * fv;
    }
  }
#pragma unroll
  for (int ct = 0; ct < 2; ct++)
    atomicAdd(&ls[wc * 32 + ct * 16 + l15], sq[ct]);
  __syncthreads();
  if (t < 64) {
    int z = isq ? 0 : 1;
    int b = isq ? (row0 >> 10) : (row0 >> 11);
    atomicAdd(&sums[z * 256 + b * 64 + t], ls[t]);
  }
}

// ---------------- l2 phase 2: scale geo_q by 1/(||q_p||*||k_p||) -----------
__global__ __launch_bounds__(256) void k_l2scaleq(
    __bf16* __restrict__ gq, const float* __restrict__ sums) {
  int chunk = blockIdx.x, b = blockIdx.y;
  unsigned* base = (unsigned*)(gq + (size_t)b * 1024 * 64) + chunk * 128 * 32;
  int t = threadIdx.x, c = t & 31, ro = t >> 5;
  float sq0 = sums[b * 64 + c * 2], sq1 = sums[b * 64 + c * 2 + 1];
  float sk0 = sums[256 + b * 64 + c * 2], sk1 = sums[256 + b * 64 + c * 2 + 1];
  float m0 = 1.f / (fmaxf(sqrtf(sq0), 1e-12f) * fmaxf(sqrtf(sk0), 1e-12f));
  float m1 = 1.f / (fmaxf(sqrtf(sq1), 1e-12f) * fmaxf(sqrtf(sk1), 1e-12f));
  for (int r = ro; r < 128; r += 8) {
    unsigned u = base[r * 32 + c];
    float f0 = __uint_as_float(u << 16) * m0;
    float f1 = __uint_as_float(u & 0xffff0000u) * m1;
    unsigned short h0 = __builtin_bit_cast(unsigned short, (__bf16)f0);
    unsigned short h1 = __builtin_bit_cast(unsigned short, (__bf16)f1);
    base[r * 32 + c] = (unsigned)h0 | ((unsigned)h1 << 16);
  }
}

// ---------------- fused QKV: qb(256) + kb(512) + vtb(512) blocks -----------
// T1 XCD swizzle; BK=64; swizzled LDS (pre-swizzled glds source). bounds 3.
__global__ __launch_bounds__(256, 3) void k_qkv(
    const __bf16* __restrict__ qin, const __bf16* __restrict__ kvin,
    const __bf16* __restrict__ twq, const __bf16* __restrict__ twk,
    const __bf16* __restrict__ twv, const float* __restrict__ qbias,
    const float* __restrict__ kbias, const float* __restrict__ vbias,
    __bf16* __restrict__ qb, __bf16* __restrict__ kb, __bf16* __restrict__ vtb) {
  int id0 = blockIdx.x;
  int id = (id0 & 7) * 160 + (id0 >> 3);  // nwg=1280=8*160, bijective
  const __bf16 *A, *Bt;
  const float* bias;
  __bf16* C;
  int my, nx, Ndim;
  bool rowbias;
  if (id < 256) {
    A = qin; Bt = twq; bias = qbias; C = qb;
    nx = id & 7; my = id >> 3; Ndim = 1024; rowbias = false;
  } else if (id < 768) {
    id -= 256;
    A = kvin; Bt = twk; bias = kbias; C = kb;
    nx = id & 7; my = id >> 3; Ndim = 1024; rowbias = false;
  } else {
    id -= 768;
    A = twv; Bt = kvin; bias = vbias; C = vtb;
    nx = id & 63; my = id >> 6; Ndim = 8192; rowbias = true;
  }
  const int Kdim = 1024;
  __shared__ __align__(16) __bf16 As[128 * 64];
  __shared__ __align__(16) __bf16 Bs[128 * 64];
  const int m0 = my * 128, n0 = nx * 128;
  const int t = threadIdx.x, lane = t & 63, w = t >> 6;
  const int quad = lane >> 4, l15 = lane & 15;
  const int wr = w >> 1, wc = w & 1;
  const int srow = lane >> 3, scol8 = ((lane & 7) ^ (lane >> 3)) * 8;
  const __bf16* aS0 = A + (size_t)(m0 + w * 32 + srow) * Kdim + scol8;
  const __bf16* bS0 = Bt + (size_t)(n0 + w * 32 + srow) * Kdim + scol8;
  __bf16* lA0 = &As[(w * 32) * 64];
  __bf16* lB0 = &Bs[(w * 32) * 64];

  f32x4 acc[4][4] = {};
  for (int k0 = 0; k0 < Kdim; k0 += 64) {
    __syncthreads();
#pragma unroll
    for (int c = 0; c < 4; c++) {
      glds16(aS0 + (size_t)c * 8 * Kdim + k0, lA0 + c * 8 * 64);
      glds16(bS0 + (size_t)c * 8 * Kdim + k0, lB0 + c * 8 * 64);
    }
    __syncthreads();
#pragma unroll
    for (int kh = 0; kh < 2; kh++) {
      bf16x8 af[4], bg[4];
#pragma unroll
      for (int rt = 0; rt < 4; rt++)
        af[rt] = *(const bf16x8*)&As[swz(wr * 64 + rt * 16 + l15, kh * 32 + quad * 8)];
#pragma unroll
      for (int ct = 0; ct < 4; ct++)
        bg[ct] = *(const bf16x8*)&Bs[swz(wc * 64 + ct * 16 + l15, kh * 32 + quad * 8)];
#pragma unroll
      for (int rt = 0; rt < 4; rt++)
#pragma unroll
        for (int ct = 0; ct < 4; ct++)
          acc[rt][ct] = mfma16(af[rt], bg[ct], acc[rt][ct]);
    }
  }
#pragma unroll
  for (int rt = 0; rt < 4; rt++) {
    int row = m0 + wr * 64 + rt * 16 + quad * 4;
#pragma unroll
    for (int ct = 0; ct < 4; ct++) {
      int col = n0 + wc * 64 + ct * 16 + l15;
      float bcol = rowbias ? 0.f : bias[col];
#pragma unroll
      for (int i = 0; i < 4; i++) {
        float vv = acc[rt][ct][i] + (rowbias ? bias[row + i] : bcol);
        C[(size_t)(row + i) * Ndim + col] = (__bf16)vv;
      }
    }
  }
}

// ---------------- big GEMM 128x128 (ff1: gelu epilogue) --------------------
// BK=64 + swizzled LDS; T1 XCD swizzle.
__global__ __launch_bounds__(256, 3) void k_gemm128g(
    const __bf16* __restrict__ A, const __bf16* __restrict__ Bt,
    const float* __restrict__ bias, __bf16* __restrict__ Cout,
    int Ndim, int Kdim) {
  __shared__ __align__(16) __bf16 As[128 * 64];
  __shared__ __align__(16) __bf16 Bs[128 * 64];
  int p = blockIdx.y * gridDim.x + blockIdx.x;  // nwg=512=8*64
  int l = (p & 7) * 64 + (p >> 3);              // T1 XCD swizzle
  const int m0 = (l >> 4) * 128, n0 = (l & 15) * 128;
  const int t = threadIdx.x, lane = t & 63, w = t >> 6;
  const int quad = lane >> 4, l15 = lane & 15;
  const int wr = w >> 1, wc = w & 1;
  const int srow = lane >> 3, scol8 = ((lane & 7) ^ (lane >> 3)) * 8;
  const __bf16* aS0 = A + (size_t)(m0 + w * 32 + srow) * Kdim + scol8;
  const __bf16* bS0 = Bt + (size_t)(n0 + w * 32 + srow) * Kdim + scol8;
  __bf16* lA0 = &As[(w * 32) * 64];
  __bf16* lB0 = &Bs[(w * 32) * 64];

  f32x4 acc[4][4] = {};
  for (int k0 = 0; k0 < Kdim; k0 += 64) {
    __syncthreads();
#pragma unroll
    for (int c = 0; c < 4; c++) {
      glds16(aS0 + (size_t)c * 8 * Kdim + k0, lA0 + c * 8 * 64);
      glds16(bS0 + (size_t)c * 8 * Kdim + k0, lB0 + c * 8 * 64);
    }
    __syncthreads();
#pragma unroll
    for (int kh = 0; kh < 2; kh++) {
      bf16x8 af[4], bg[4];
#pragma unroll
      for (int rt = 0; rt < 4; rt++)
        af[rt] = *(const bf16x8*)&As[swz(wr * 64 + rt * 16 + l15, kh * 32 + quad * 8)];
#pragma unroll
      for (int ct = 0; ct < 4; ct++)
        bg[ct] = *(const bf16x8*)&Bs[swz(wc * 64 + ct * 16 + l15, kh * 32 + quad * 8)];
#pragma unroll
      for (int rt = 0; rt < 4; rt++)
#pragma unroll
        for (int ct = 0; ct < 4; ct++)
          acc[rt][ct] = mfma16(af[rt], bg[ct], acc[rt][ct]);
    }
  }
#pragma unroll
  for (int rt = 0; rt < 4; rt++) {
    int row = m0 + wr * 64 + rt * 16 + quad * 4;
#pragma unroll
    for (int ct = 0; ct < 4; ct++) {
      int col = n0 + wc * 64 + ct * 16 + l15;
      float bcol = bias[col];
#pragma unroll
      for (int i = 0; i < 4; i++) {
        float vv = acc[rt][ct][i] + bcol;
        Cout[(size_t)(row + i) * Ndim + col] =
            (__bf16)(0.5f * vv * (1.f + erff(vv * 0.70710678118f)));
      }
    }
  }
}

// ---------------- GEMM 128x64 tile (wo / ff2): +bias +resid -> f32 ---------
// BK=64 + swizzled LDS; bounds 3.
__global__ __launch_bounds__(256, 3) void k_gemmn64(
    const __bf16* __restrict__ A, const __bf16* __restrict__ Bt,
    const float* __restrict__ bias, const float* __restrict__ resid,
    float* __restrict__ Cout, int Ndim, int Kdim) {
  __shared__ __align__(16) __bf16 As[128 * 64];
  __shared__ __align__(16) __bf16 Bs[64 * 64];
  int p = blockIdx.y * gridDim.x + blockIdx.x;  // nwg=512=8*64
  int l = (p & 7) * 64 + (p >> 3);              // T1 XCD swizzle
  const int m0 = (l >> 4) * 128, n0 = (l & 15) * 64;
  const int t = threadIdx.x, lane = t & 63, w = t >> 6;
  const int quad = lane >> 4, l15 = lane & 15;
  const int wr = w >> 1, wc = w & 1;
  const int srow = lane >> 3, scol8 = ((lane & 7) ^ (lane >> 3)) * 8;
  const __bf16* aS0 = A + (size_t)(m0 + w * 32 + srow) * Kdim + scol8;
  const __bf16* bS0 = Bt + (size_t)(n0 + w * 16 + srow) * Kdim + scol8;
  __bf16* lA0 = &As[(w * 32) * 64];
  __bf16* lB0 = &Bs[(w * 16) * 64];

  f32x4 acc[4][2] = {};
  for (int k0 = 0; k0 < Kdim; k0 += 64) {
    __syncthreads();
#pragma unroll
    for (int c = 0; c < 4; c++)
      glds16(aS0 + (size_t)c * 8 * Kdim + k0, lA0 + c * 8 * 64);
#pragma unroll
    for (int c = 0; c < 2; c++)
      glds16(bS0 + (size_t)c * 8 * Kdim + k0, lB0 + c * 8 * 64);
    __syncthreads();
#pragma unroll
    for (int kh = 0; kh < 2; kh++) {
      bf16x8 af[4], bg[2];
#pragma unroll
      for (int rt = 0; rt < 4; rt++)
        af[rt] = *(const bf16x8*)&As[swz(wr * 64 + rt * 16 + l15, kh * 32 + quad * 8)];
#pragma unroll
      for (int ct = 0; ct < 2; ct++)
        bg[ct] = *(const bf16x8*)&Bs[swz(wc * 32 + ct * 16 + l15, kh * 32 + quad * 8)];
#pragma unroll
      for (int rt = 0; rt < 4; rt++)
#pragma unroll
        for (int ct = 0; ct < 2; ct++)
          acc[rt][ct] = mfma16(af[rt], bg[ct], acc[rt][ct]);
    }
  }
#pragma unroll
  for (int rt = 0; rt < 4; rt++) {
    int row = m0 + wr * 64 + rt * 16 + quad * 4;
#pragma unroll
    for (int ct = 0; ct < 2; ct++) {
      int col = n0 + wc * 32 + ct * 16 + l15;
      float bcol = bias[col];
#pragma unroll
      for (int i = 0; i < 4; i++) {
        size_t idx = (size_t)(row + i) * Ndim + col;
        Cout[idx] = acc[rt][ct][i] + bcol + resid[idx];
      }
    }
  }
}

// ---------------- flash attention: S^T form (R10 body, byte-exact) ---------
__global__ __launch_bounds__(256, 2) void k_flash(
    const __bf16* __restrict__ Q, const __bf16* __restrict__ K,
    const __bf16* __restrict__ Vt, const __bf16* __restrict__ Gq,
    const __bf16* __restrict__ Gk, const float* __restrict__ als,
    const float* __restrict__ psc, const float* __restrict__ nsc,
    __bf16* __restrict__ Out) {
  const int o = blockIdx.x;
  const int bh = o & 63, x = o >> 6;
  const int b = bh & 3, h = bh >> 2;
  const int t = threadIdx.x, w = t >> 6, lane = t & 63;
  const int quad = lane >> 4, l15 = lane & 15;
  const int row0 = x * 128 + w * 32;
  const float LOG2E = 1.44269504089f;
  const float sc2 = __expf(als[0]) * 0.125f * LOG2E;
  const float pos2 = psc[0] * LOG2E, neg2 = nsc[0] * LOG2E;

  __shared__ __align__(16) __bf16 Ks[64 * 64];
  __shared__ __align__(16) __bf16 Gs[64 * 64];
  __shared__ __align__(16) __bf16 Vs[64 * 64];
  __shared__ __align__(16) __bf16 Ps[4][32 * 64];

  const __bf16* Qb = Q + ((size_t)(b * NN + row0)) * DB + h * DHD;
  const __bf16* Kb = K + ((size_t)b * NM) * DB + h * DHD;
  const __bf16* Vb = Vt + (size_t)(h * DHD) * (NB * NM) + (size_t)b * NM;
  const __bf16* Gqb = Gq + (size_t)(b * NN + row0) * DP;
  const __bf16* Gkb = Gk + (size_t)b * NM * DP;

  // staging: thread t covers rows r0, r0+32 at 16B chunk (swizzled dest)
  const int r0 = t >> 3, gc = (t & 7) * 8;
  const int sw0 = swz(r0, gc), sw1 = sw0 + 32 * 64;  // (r0+32)&7 == r0&7
  const int r1 = r0 + 32;

  bf16x8 qf[2][2], gqf[2][2];
#pragma unroll
  for (int rt = 0; rt < 2; rt++)
#pragma unroll
    for (int ks = 0; ks < 2; ks++) {
      qf[rt][ks] = *(const bf16x8*)(Qb + (size_t)(rt * 16 + l15) * DB + ks * 32 + quad * 8);
      gqf[rt][ks] = *(const bf16x8*)(Gqb + (size_t)(rt * 16 + l15) * DP + ks * 32 + quad * 8);
    }

  // prefetch first slab
  bf16x8 kst0 = *(const bf16x8*)(Kb + (size_t)r0 * DB + gc);
  bf16x8 kst1 = *(const bf16x8*)(Kb + (size_t)r1 * DB + gc);
  bf16x8 gst0 = *(const bf16x8*)(Gkb + (size_t)r0 * DP + gc);
  bf16x8 gst1 = *(const bf16x8*)(Gkb + (size_t)r1 * DP + gc);
  bf16x8 vst0 = *(const bf16x8*)(Vb + (size_t)r0 * (NB * NM) + gc);
  bf16x8 vst1 = *(const bf16x8*)(Vb + (size_t)r1 * (NB * NM) + gc);

  float lrowq[2] = {};
  f32x4 oacc[2][4] = {};
  f32x4 z4 = {0.f, 0.f, 0.f, 0.f};

  for (int m0 = 0; m0 < NM; m0 += 64) {
    __syncthreads();  // prior iter's tile reads complete
    *(bf16x8*)&Ks[sw0] = kst0;
    *(bf16x8*)&Ks[sw1] = kst1;
    *(bf16x8*)&Gs[sw0] = gst0;
    *(bf16x8*)&Gs[sw1] = gst1;
    *(bf16x8*)&Vs[sw0] = vst0;
    *(bf16x8*)&Vs[sw1] = vst1;
    __syncthreads();  // tiles visible
    if (m0 + 64 < NM) {  // prefetch next slab during compute
      kst0 = *(const bf16x8*)(Kb + (size_t)(m0 + 64 + r0) * DB + gc);
      kst1 = *(const bf16x8*)(Kb + (size_t)(m0 + 64 + r1) * DB + gc);
      gst0 = *(const bf16x8*)(Gkb + (size_t)(m0 + 64 + r0) * DP + gc);
      gst1 = *(const bf16x8*)(Gkb + (size_t)(m0 + 64 + r1) * DP + gc);
      vst0 = *(const bf16x8*)(Vb + (size_t)r0 * (NB * NM) + m0 + 64 + gc);
      vst1 = *(const bf16x8*)(Vb + (size_t)r1 * (NB * NM) + m0 + 64 + gc);
    }
    bf16x8 kf[4][2], gkf[4][2];
#pragma unroll
    for (int ct = 0; ct < 4; ct++)
#pragma unroll
      for (int ks = 0; ks < 2; ks++) {
        int off = swz(ct * 16 + l15, ks * 32 + quad * 8);
        kf[ct][ks] = *(const bf16x8*)&Ks[off];
        gkf[ct][ks] = *(const bf16x8*)&Gs[off];
      }
    // S^T tiles: D[m-block ct][n-block rt], A=K rows (m), B=Q rows (n).
    // C-layout: col = n = l15, row = m = quad*4+i -> 4 consecutive m/lane.
#pragma unroll
    for (int ct = 0; ct < 4; ct++)
#pragma unroll
      for (int rt = 0; rt < 2; rt++) {
        f32x4 s = mfma16(kf[ct][1], qf[rt][1], mfma16(kf[ct][0], qf[rt][0], z4));
        f32x4 bg = mfma16(gkf[ct][1], gqf[rt][1], mfma16(gkf[ct][0], gqf[rt][0], z4));
        bf16x4 pk;
        float part = 0.f;
#pragma unroll
        for (int i = 0; i < 4; i++) {
          float bb = bg[i];
          float scl = bb > 0.f ? pos2 : neg2;
          float p = __builtin_amdgcn_exp2f(fmaf(bb, scl, s[i] * sc2));
          part += p;
          pk[i] = (__bf16)p;
        }
        lrowq[rt] += part;
        *(bf16x4*)&Ps[w][swz(rt * 16 + l15, ct * 16 + quad * 4)] = pk;
      }
    // PV: A = P[n][m] (b128 from swizzled per-wave tile), B = V^T[d][m]
    bf16x8 pf[2][2], vf[4][2];
#pragma unroll
    for (int rt = 0; rt < 2; rt++)
#pragma unroll
      for (int ms = 0; ms < 2; ms++)
        pf[rt][ms] = *(const bf16x8*)&Ps[w][swz(rt * 16 + l15, ms * 32 + quad * 8)];
#pragma unroll
    for (int dt = 0; dt < 4; dt++)
#pragma unroll
      for (int ms = 0; ms < 2; ms++)
        vf[dt][ms] = *(const bf16x8*)&Vs[swz(dt * 16 + l15, ms * 32 + quad * 8)];
#pragma unroll
    for (int rt = 0; rt < 2; rt++)
#pragma unroll
      for (int dt = 0; dt < 4; dt++) {
        oacc[rt][dt] = mfma16(pf[rt][0], vf[dt][0], oacc[rt][dt]);
        oacc[rt][dt] = mfma16(pf[rt][1], vf[dt][1], oacc[rt][dt]);
      }
  }
  // lrowq[rt] holds this lane's quad-share for n = rt*16+l15: sum over quads,
  // then redistribute to the oacc layout (n = rt*16+quad*4+i) via shuffles.
  float ltot[2];
#pragma unroll
  for (int rt = 0; rt < 2; rt++) {
    float l = lrowq[rt];
    l += __shfl_xor(l, 16, 64);
    l += __shfl_xor(l, 32, 64);
    ltot[rt] = l;
  }
#pragma unroll
  for (int rt = 0; rt < 2; rt++)
#pragma unroll
    for (int i = 0; i < 4; i++) {
      float li = __shfl(ltot[rt], quad * 4 + i, 64);
      float inv = 1.f / li;
#pragma unroll
      for (int dt = 0; dt < 4; dt++)
        Out[(size_t)(b * NN + row0 + rt * 16 + quad * 4 + i) * DB + h * DHD + dt * 16 + l15] =
            (__bf16)(oacc[rt][dt][i] * inv);
    }
}

// ---------------------------------------------------------------------------
extern "C" void kernel_launch(void* const* d_in, const int* in_sizes, int n_in,
                              void* d_out, int out_size, void* d_ws, size_t ws_size,
                              hipStream_t stream) {
  const float* dataset = (const float*)d_in[0];
  const float* visual = (const float*)d_in[1];
  const float* wq_w = (const float*)d_in[2];
  const float* wq_b = (const float*)d_in[3];
  const float* wk_w = (const float*)d_in[4];
  const float* wk_b = (const float*)d_in[5];
  const float* wv_w = (const float*)d_in[6];
  const float* wv_b = (const float*)d_in[7];
  const float* wo_w = (const float*)d_in[8];
  const float* wo_b = (const float*)d_in[9];
  const float* gq_w = (const float*)d_in[10];
  const float* gq_b = (const float*)d_in[11];
  const float* gk_w = (const float*)d_in[12];
  const float* gk_b = (const float*)d_in[13];
  const float* pos_scale = (const float*)d_in[14];
  const float* neg_scale = (const float*)d_in[15];
  const float* als = (const float*)d_in[16];
  const float* ln_q_g = (const float*)d_in[17];
  const float* ln_q_b = (const float*)d_in[18];
  const float* ln_kv_g = (const float*)d_in[19];
  const float* ln_kv_b = (const float*)d_in[20];
  const float* ln_out_g = (const float*)d_in[21];
  const float* ln_out_b = (const float*)d_in[22];
  const float* ff1_w = (const float*)d_in[23];
  const float* ff1_b = (const float*)d_in[24];
  const float* ff2_w = (const float*)d_in[25];
  const float* ff2_b = (const float*)d_in[26];

  char* ws = (char*)d_ws;
  size_t off = 0;
  auto alloc = [&](size_t bytes) {
    size_t o = off;
    off += (bytes + 255) & ~(size_t)255;
    return o;
  };
  __bf16* t_wq = (__bf16*)(ws + alloc((size_t)1024 * 1024 * 2));
  __bf16* t_wk = (__bf16*)(ws + alloc((size_t)1024 * 1024 * 2));
  __bf16* t_wv = (__bf16*)(ws + alloc((size_t)1024 * 1024 * 2));
  __bf16* t_wo = (__bf16*)(ws + alloc((size_t)1024 * 1024 * 2));
  __bf16* t_ff1 = (__bf16*)(ws + alloc((size_t)2048 * 1024 * 2));
  __bf16* t_ff2 = (__bf16*)(ws + alloc((size_t)1024 * 2048 * 2));
  __bf16* t_gq = (__bf16*)(ws + alloc((size_t)64 * 1024 * 2));
  __bf16* t_gk = (__bf16*)(ws + alloc((size_t)64 * 1024 * 2));
  size_t qin_off = alloc((size_t)4096 * 1024 * 2);   // aliased as hbuf later
  size_t kvin_off = alloc((size_t)8192 * 1024 * 2);  // aliased as out1(f32) later
  __bf16* qin = (__bf16*)(ws + qin_off);
  __bf16* kvin = (__bf16*)(ws + kvin_off);
  __bf16* geoq = (__bf16*)(ws + alloc((size_t)4096 * 64 * 2));
  __bf16* geok = (__bf16*)(ws + alloc((size_t)8192 * 64 * 2));
  float* sums = (float*)(ws + alloc((size_t)2 * 4 * 64 * 4));
  __bf16* qb = (__bf16*)(ws + alloc((size_t)4096 * 1024 * 2));
  __bf16* kb = (__bf16*)(ws + alloc((size_t)8192 * 1024 * 2));
  __bf16* vtb = (__bf16*)(ws + alloc((size_t)1024 * 8192 * 2));  // V^T [ch][tok]
  __bf16* attn = (__bf16*)(ws + alloc((size_t)4096 * 1024 * 2));
  __bf16* ffh = (__bf16*)(ws + alloc((size_t)4096 * 2048 * 2));
  // aliases (lifetimes disjoint):
  float* out1 = (float*)(ws + kvin_off);   // f32 [4096,1024] over kv_in
  __bf16* hbuf = (__bf16*)(ws + qin_off);  // bf16 [4096,1024] over q_in
  float* outp = (float*)d_out;

  dim3 blk(256);
  // 1. all weight transposes (grid-stride, 2080 blocks)
  k_transpose_all<<<2080, blk, 0, stream>>>(wq_w, wk_w, wv_w, wo_w, ff1_w, ff2_w,
                                            gq_w, gk_w, t_wq, t_wk, t_wv, t_wo,
                                            t_ff1, t_ff2, t_gq, t_gk);
  // 2. both input layernorms (grid-stride, 2048 blocks)
  k_layernorm2<<<2048, blk, 0, stream>>>(dataset, ln_q_g, ln_q_b, qin,
                                         visual, ln_kv_g, ln_kv_b, kvin);
  // 3. geo path (l2sum fused into geo epilogue)
  hipMemsetAsync(sums, 0, 2 * 4 * 64 * 4, stream);
  k_geo<<<384, blk, 0, stream>>>(qin, kvin, t_gq, t_gk, gq_b, gk_b, geoq, geok,
                                 sums);
  k_l2scaleq<<<dim3(8, 4), blk, 0, stream>>>(geoq, sums);
  // 4. fused QKV projections (XCD-swizzled, BK=64 swizzled LDS)
  k_qkv<<<1280, blk, 0, stream>>>(qin, kvin, t_wq, t_wk, t_wv,
                                  wq_b, wk_b, wv_b, qb, kb, vtb);
  // 5. flash attention (bias fused, S^T form, R10 body)
  k_flash<<<512, blk, 0, stream>>>(qb, kb, vtb, geoq, geok, als,
                                   pos_scale, neg_scale, attn);
  // 6. output projection + residual, LN, FFN (XCD-swizzled, BK=64 swz LDS)
  k_gemmn64<<<dim3(16, 32), blk, 0, stream>>>(attn, t_wo, wo_b, dataset, out1,
                                              1024, 1024);
  k_layernorm<<<2048, blk, 0, stream>>>(out1, ln_out_g, ln_out_b, hbuf);
  k_gemm128g<<<dim3(16, 32), blk, 0, stream>>>(hbuf, t_ff1, ff1_b, ffh,
                                               2048, 1024);
  k_gemmn64<<<dim3(16, 32), blk, 0, stream>>>(ffh, t_ff2, ff2_b, out1, outp,
                                              1024, 2048);
}

// Round 12
// 418.698 us; speedup vs baseline: 1.0353x; 1.0353x over previous
//
#include <hip/hip_runtime.h>

// ---------------------------------------------------------------------------
// BiasCrossAttentionFusion on gfx950 — round 18 = round 16 (session best,
// 421.3us), byte-exact revert of R17's grid-stride regression (+12us:
// streaming kernels want max independent blocks, not grid-stride+barrier).
// Final configuration:
//   - flash: R10 body untouched (~82us structural floor; 5 restructure
//     attempts R7-R12 all regressed it)
//   - all 4 GEMMs: BK=64 + XOR-swizzled LDS staging (pre-swizzled glds
//     source, m201 both-sides pattern) + T1 XCD swizzle (~34us total vs R6)
//   - l2sum fused into k_geo epilogue; l2scale applied to geoq (0.5MB)
//   - tiny kernels: one row/tile per block (12288/8320/4096 blocks)
// ---------------------------------------------------------------------------

typedef __bf16 bf16x8 __attribute__((ext_vector_type(8)));
typedef __bf16 bf16x4 __attribute__((ext_vector_type(4)));
typedef float  f32x4  __attribute__((ext_vector_type(4)));

__device__ inline f32x4 mfma16(bf16x8 a, bf16x8 b, f32x4 c) {
  return __builtin_amdgcn_mfma_f32_16x16x32_bf16(a, b, c, 0, 0, 0);
}

__device__ inline void glds16(const void* g, void* l) {
  __builtin_amdgcn_global_load_lds(
      (const __attribute__((address_space(1))) void*)g,
      (__attribute__((address_space(3))) void*)l, 16, 0, 0);
}

// swizzled LDS offset for a 64-elem bf16 row: 16B-chunk index XOR (row&7)
__device__ inline int swz(int row, int col) {
  return row * 64 + ((((col >> 3) ^ (row & 7)) << 3) | (col & 7));
}

#define DB 1024
#define DH 16
#define DHD 64
#define DP 64
#define NB 4
#define NN 1024
#define NM 2048

// ---------------- all weight transposes (f32 [K,O] -> bf16 [O,K]) ----------
__global__ __launch_bounds__(256) void k_transpose_all(
    const float* __restrict__ w0, const float* __restrict__ w1,
    const float* __restrict__ w2, const float* __restrict__ w3,
    const float* __restrict__ f1, const float* __restrict__ f2,
    const float* __restrict__ g0, const float* __restrict__ g1,
    __bf16* __restrict__ o0, __bf16* __restrict__ o1,
    __bf16* __restrict__ o2, __bf16* __restrict__ o3,
    __bf16* __restrict__ of1, __bf16* __restrict__ of2,
    __bf16* __restrict__ og0, __bf16* __restrict__ og1) {
  __shared__ float tile[32][33];
  int id = blockIdx.x;
  const float* in;
  __bf16* out;
  int K, O, x, y;
  if (id < 4096) {
    int mi = id >> 10, r = id & 1023;
    in = mi == 0 ? w0 : mi == 1 ? w1 : mi == 2 ? w2 : w3;
    out = mi == 0 ? o0 : mi == 1 ? o1 : mi == 2 ? o2 : o3;
    K = 1024; O = 1024; x = r & 31; y = r >> 5;
  } else if (id < 6144) {
    int r = id - 4096; in = f1; out = of1; K = 1024; O = 2048; x = r & 63; y = r >> 6;
  } else if (id < 8192) {
    int r = id - 6144; in = f2; out = of2; K = 2048; O = 1024; x = r & 31; y = r >> 5;
  } else if (id < 8256) {
    int r = id - 8192; in = g0; out = og0; K = 1024; O = 64; x = r & 1; y = r >> 1;
  } else {
    int r = id - 8256; in = g1; out = og1; K = 1024; O = 64; x = r & 1; y = r >> 1;
  }
  int k0 = y * 32, o0c = x * 32;
  int tx = threadIdx.x & 31, ty = threadIdx.x >> 5;
#pragma unroll
  for (int r = ty; r < 32; r += 8)
    tile[r][tx] = in[(size_t)(k0 + r) * O + (o0c + tx)];
  __syncthreads();
#pragma unroll
  for (int r = ty; r < 32; r += 8)
    out[(size_t)(o0c + r) * K + (k0 + tx)] = (__bf16)tile[tx][r];
}

// ---------------- LayerNorm D=1024, one block/row, bf16 out ----------------
__device__ inline void ln_body(const float* __restrict__ x,
                               const float* __restrict__ g,
                               const float* __restrict__ bb,
                               __bf16* __restrict__ y, size_t row) {
  int t = threadIdx.x;
  float4 v = ((const float4*)(x + row * 1024))[t];
  float s = v.x + v.y + v.z + v.w;
  float ss = v.x * v.x + v.y * v.y + v.z * v.z + v.w * v.w;
#pragma unroll
  for (int o = 32; o; o >>= 1) {
    s += __shfl_down(s, o, 64);
    ss += __shfl_down(ss, o, 64);
  }
  __shared__ float r1[4], r2[4];
  if ((t & 63) == 0) { r1[t >> 6] = s; r2[t >> 6] = ss; }
  __syncthreads();
  s = r1[0] + r1[1] + r1[2] + r1[3];
  ss = r2[0] + r2[1] + r2[2] + r2[3];
  float mu = s * (1.f / 1024.f);
  float rstd = rsqrtf(ss * (1.f / 1024.f) - mu * mu + 1e-5f);
  float4 gv = ((const float4*)g)[t];
  float4 bv = ((const float4*)bb)[t];
  __bf16* yr = y + row * 1024 + t * 4;
  yr[0] = (__bf16)((v.x - mu) * rstd * gv.x + bv.x);
  yr[1] = (__bf16)((v.y - mu) * rstd * gv.y + bv.y);
  yr[2] = (__bf16)((v.z - mu) * rstd * gv.z + bv.z);
  yr[3] = (__bf16)((v.w - mu) * rstd * gv.w + bv.w);
}

__global__ __launch_bounds__(256) void k_layernorm(
    const float* __restrict__ x, const float* __restrict__ g,
    const float* __restrict__ bb, __bf16* __restrict__ y) {
  ln_body(x, g, bb, y, blockIdx.x);
}

__global__ __launch_bounds__(256) void k_layernorm2(
    const float* __restrict__ x1, const float* __restrict__ g1,
    const float* __restrict__ b1, __bf16* __restrict__ y1,
    const float* __restrict__ x2, const float* __restrict__ g2,
    const float* __restrict__ b2, __bf16* __restrict__ y2) {
  int row = blockIdx.x;
  if (row < 4096) ln_body(x1, g1, b1, y1, row);
  else ln_body(x2, g2, b2, y2, row - 4096);
}

// ---------------- geo projections + FUSED l2 column sum-of-squares ---------
// q(128 blk) + kv(256 blk), 32x64 tiles. Epilogue squares the bf16-ROUNDED
// outputs (matches old l2sum semantics), LDS-reduces per channel, one
// global atomicAdd per channel per block.
__global__ __launch_bounds__(256) void k_geo(
    const __bf16* __restrict__ qin, const __bf16* __restrict__ kvin,
    const __bf16* __restrict__ gqw, const __bf16* __restrict__ gkw,
    const float* __restrict__ gqb, const float* __restrict__ gkb,
    __bf16* __restrict__ geoq, __bf16* __restrict__ geok,
    float* __restrict__ sums) {
  const int blk = blockIdx.x;
  const bool isq = blk < 128;
  const __bf16* A = isq ? qin : kvin;
  const __bf16* Bt = isq ? gqw : gkw;
  const float* bias = isq ? gqb : gkb;
  __bf16* C = isq ? geoq : geok;
  const int row0 = (isq ? blk : blk - 128) * 32;
  __shared__ __align__(16) __bf16 As[32][72], Bs[64][72];
  __shared__ float ls[64];
  const int t = threadIdx.x, lane = t & 63, w = t >> 6;
  const int quad = lane >> 4, l15 = lane & 15;
  const int wr = w >> 1, wc = w & 1;
  const int sr = t >> 3, skc = (t & 7) * 8;
  const __bf16* aP = A + (size_t)(row0 + sr) * 1024 + skc;
  const __bf16* bP0 = Bt + (size_t)sr * 1024 + skc;
  const __bf16* bP1 = Bt + (size_t)(sr + 32) * 1024 + skc;
  bf16x8 av = *(const bf16x8*)aP;
  bf16x8 bv0 = *(const bf16x8*)bP0;
  bf16x8 bv1 = *(const bf16x8*)bP1;
  f32x4 acc[2] = {};
  for (int k0 = 0; k0 < 1024; k0 += 64) {
    __syncthreads();
    *(bf16x8*)&As[sr][skc] = av;
    *(bf16x8*)&Bs[sr][skc] = bv0;
    *(bf16x8*)&Bs[sr + 32][skc] = bv1;
    __syncthreads();
    if (k0 + 64 < 1024) {
      av = *(const bf16x8*)(aP + k0 + 64);
      bv0 = *(const bf16x8*)(bP0 + k0 + 64);
      bv1 = *(const bf16x8*)(bP1 + k0 + 64);
    }
#pragma unroll
    for (int ks = 0; ks < 2; ks++) {
      bf16x8 af = *(const bf16x8*)&As[wr * 16 + l15][ks * 32 + quad * 8];
#pragma unroll
      for (int ct = 0; ct < 2; ct++) {
        bf16x8 bfr = *(const bf16x8*)&Bs[wc * 32 + ct * 16 + l15][ks * 32 + quad * 8];
        acc[ct] = mfma16(af, bfr, acc[ct]);
      }
    }
  }
  if (t < 64) ls[t] = 0.f;
  __syncthreads();
  float sq[2] = {0.f, 0.f};
#pragma unroll
  for (int ct = 0; ct < 2; ct++) {
    int col = wc * 32 + ct * 16 + l15;
    float bc = bias[col];
#pragma unroll
    for (int i = 0; i < 4; i++) {
      int row = row0 + wr * 16 + quad * 4 + i;
      __bf16 hv = (__bf16)(acc[ct][i] + bc);
      C[(size_t)row * 64 + col] = hv;
      float fv = (float)hv;
      sq[ct] += fv * fv;
    }
  }
#pragma unroll
  for (int ct = 0; ct < 2; ct++)
    atomicAdd(&ls[wc * 32 + ct * 16 + l15], sq[ct]);
  __syncthreads();
  if (t < 64) {
    int z = isq ? 0 : 1;
    int b = isq ? (row0 >> 10) : (row0 >> 11);
    atomicAdd(&sums[z * 256 + b * 64 + t], ls[t]);
  }
}

// ---------------- l2 phase 2: scale geo_q by 1/(||q_p||*||k_p||) -----------
__global__ __launch_bounds__(256) void k_l2scaleq(
    __bf16* __restrict__ gq, const float* __restrict__ sums) {
  int chunk = blockIdx.x, b = blockIdx.y;
  unsigned* base = (unsigned*)(gq + (size_t)b * 1024 * 64) + chunk * 128 * 32;
  int t = threadIdx.x, c = t & 31, ro = t >> 5;
  float sq0 = sums[b * 64 + c * 2], sq1 = sums[b * 64 + c * 2 + 1];
  float sk0 = sums[256 + b * 64 + c * 2], sk1 = sums[256 + b * 64 + c * 2 + 1];
  float m0 = 1.f / (fmaxf(sqrtf(sq0), 1e-12f) * fmaxf(sqrtf(sk0), 1e-12f));
  float m1 = 1.f / (fmaxf(sqrtf(sq1), 1e-12f) * fmaxf(sqrtf(sk1), 1e-12f));
  for (int r = ro; r < 128; r += 8) {
    unsigned u = base[r * 32 + c];
    float f0 = __uint_as_float(u << 16) * m0;
    float f1 = __uint_as_float(u & 0xffff0000u) * m1;
    unsigned short h0 = __builtin_bit_cast(unsigned short, (__bf16)f0);
    unsigned short h1 = __builtin_bit_cast(unsigned short, (__bf16)f1);
    base[r * 32 + c] = (unsigned)h0 | ((unsigned)h1 << 16);
  }
}

// ---------------- fused QKV: qb(256) + kb(512) + vtb(512) blocks -----------
// T1 XCD swizzle; BK=64; swizzled LDS (pre-swizzled glds source). bounds 3.
__global__ __launch_bounds__(256, 3) void k_qkv(
    const __bf16* __restrict__ qin, const __bf16* __restrict__ kvin,
    const __bf16* __restrict__ twq, const __bf16* __restrict__ twk,
    const __bf16* __restrict__ twv, const float* __restrict__ qbias,
    const float* __restrict__ kbias, const float* __restrict__ vbias,
    __bf16* __restrict__ qb, __bf16* __restrict__ kb, __bf16* __restrict__ vtb) {
  int id0 = blockIdx.x;
  int id = (id0 & 7) * 160 + (id0 >> 3);  // nwg=1280=8*160, bijective
  const __bf16 *A, *Bt;
  const float* bias;
  __bf16* C;
  int my, nx, Ndim;
  bool rowbias;
  if (id < 256) {
    A = qin; Bt = twq; bias = qbias; C = qb;
    nx = id & 7; my = id >> 3; Ndim = 1024; rowbias = false;
  } else if (id < 768) {
    id -= 256;
    A = kvin; Bt = twk; bias = kbias; C = kb;
    nx = id & 7; my = id >> 3; Ndim = 1024; rowbias = false;
  } else {
    id -= 768;
    A = twv; Bt = kvin; bias = vbias; C = vtb;
    nx = id & 63; my = id >> 6; Ndim = 8192; rowbias = true;
  }
  const int Kdim = 1024;
  __shared__ __align__(16) __bf16 As[128 * 64];
  __shared__ __align__(16) __bf16 Bs[128 * 64];
  const int m0 = my * 128, n0 = nx * 128;
  const int t = threadIdx.x, lane = t & 63, w = t >> 6;
  const int quad = lane >> 4, l15 = lane & 15;
  const int wr = w >> 1, wc = w & 1;
  const int srow = lane >> 3, scol8 = ((lane & 7) ^ (lane >> 3)) * 8;
  const __bf16* aS0 = A + (size_t)(m0 + w * 32 + srow) * Kdim + scol8;
  const __bf16* bS0 = Bt + (size_t)(n0 + w * 32 + srow) * Kdim + scol8;
  __bf16* lA0 = &As[(w * 32) * 64];
  __bf16* lB0 = &Bs[(w * 32) * 64];

  f32x4 acc[4][4] = {};
  for (int k0 = 0; k0 < Kdim; k0 += 64) {
    __syncthreads();
#pragma unroll
    for (int c = 0; c < 4; c++) {
      glds16(aS0 + (size_t)c * 8 * Kdim + k0, lA0 + c * 8 * 64);
      glds16(bS0 + (size_t)c * 8 * Kdim + k0, lB0 + c * 8 * 64);
    }
    __syncthreads();
#pragma unroll
    for (int kh = 0; kh < 2; kh++) {
      bf16x8 af[4], bg[4];
#pragma unroll
      for (int rt = 0; rt < 4; rt++)
        af[rt] = *(const bf16x8*)&As[swz(wr * 64 + rt * 16 + l15, kh * 32 + quad * 8)];
#pragma unroll
      for (int ct = 0; ct < 4; ct++)
        bg[ct] = *(const bf16x8*)&Bs[swz(wc * 64 + ct * 16 + l15, kh * 32 + quad * 8)];
#pragma unroll
      for (int rt = 0; rt < 4; rt++)
#pragma unroll
        for (int ct = 0; ct < 4; ct++)
          acc[rt][ct] = mfma16(af[rt], bg[ct], acc[rt][ct]);
    }
  }
#pragma unroll
  for (int rt = 0; rt < 4; rt++) {
    int row = m0 + wr * 64 + rt * 16 + quad * 4;
#pragma unroll
    for (int ct = 0; ct < 4; ct++) {
      int col = n0 + wc * 64 + ct * 16 + l15;
      float bcol = rowbias ? 0.f : bias[col];
#pragma unroll
      for (int i = 0; i < 4; i++) {
        float vv = acc[rt][ct][i] + (rowbias ? bias[row + i] : bcol);
        C[(size_t)(row + i) * Ndim + col] = (__bf16)vv;
      }
    }
  }
}

// ---------------- big GEMM 128x128 (ff1: gelu epilogue) --------------------
// BK=64 + swizzled LDS; T1 XCD swizzle.
__global__ __launch_bounds__(256, 3) void k_gemm128g(
    const __bf16* __restrict__ A, const __bf16* __restrict__ Bt,
    const float* __restrict__ bias, __bf16* __restrict__ Cout,
    int Ndim, int Kdim) {
  __shared__ __align__(16) __bf16 As[128 * 64];
  __shared__ __align__(16) __bf16 Bs[128 * 64];
  int p = blockIdx.y * gridDim.x + blockIdx.x;  // nwg=512=8*64
  int l = (p & 7) * 64 + (p >> 3);              // T1 XCD swizzle
  const int m0 = (l >> 4) * 128, n0 = (l & 15) * 128;
  const int t = threadIdx.x, lane = t & 63, w = t >> 6;
  const int quad = lane >> 4, l15 = lane & 15;
  const int wr = w >> 1, wc = w & 1;
  const int srow = lane >> 3, scol8 = ((lane & 7) ^ (lane >> 3)) * 8;
  const __bf16* aS0 = A + (size_t)(m0 + w * 32 + srow) * Kdim + scol8;
  const __bf16* bS0 = Bt + (size_t)(n0 + w * 32 + srow) * Kdim + scol8;
  __bf16* lA0 = &As[(w * 32) * 64];
  __bf16* lB0 = &Bs[(w * 32) * 64];

  f32x4 acc[4][4] = {};
  for (int k0 = 0; k0 < Kdim; k0 += 64) {
    __syncthreads();
#pragma unroll
    for (int c = 0; c < 4; c++) {
      glds16(aS0 + (size_t)c * 8 * Kdim + k0, lA0 + c * 8 * 64);
      glds16(bS0 + (size_t)c * 8 * Kdim + k0, lB0 + c * 8 * 64);
    }
    __syncthreads();
#pragma unroll
    for (int kh = 0; kh < 2; kh++) {
      bf16x8 af[4], bg[4];
#pragma unroll
      for (int rt = 0; rt < 4; rt++)
        af[rt] = *(const bf16x8*)&As[swz(wr * 64 + rt * 16 + l15, kh * 32 + quad * 8)];
#pragma unroll
      for (int ct = 0; ct < 4; ct++)
        bg[ct] = *(const bf16x8*)&Bs[swz(wc * 64 + ct * 16 + l15, kh * 32 + quad * 8)];
#pragma unroll
      for (int rt = 0; rt < 4; rt++)
#pragma unroll
        for (int ct = 0; ct < 4; ct++)
          acc[rt][ct] = mfma16(af[rt], bg[ct], acc[rt][ct]);
    }
  }
#pragma unroll
  for (int rt = 0; rt < 4; rt++) {
    int row = m0 + wr * 64 + rt * 16 + quad * 4;
#pragma unroll
    for (int ct = 0; ct < 4; ct++) {
      int col = n0 + wc * 64 + ct * 16 + l15;
      float bcol = bias[col];
#pragma unroll
      for (int i = 0; i < 4; i++) {
        float vv = acc[rt][ct][i] + bcol;
        Cout[(size_t)(row + i) * Ndim + col] =
            (__bf16)(0.5f * vv * (1.f + erff(vv * 0.70710678118f)));
      }
    }
  }
}

// ---------------- GEMM 128x64 tile (wo / ff2): +bias +resid -> f32 ---------
// BK=64 + swizzled LDS; bounds 3.
__global__ __launch_bounds__(256, 3) void k_gemmn64(
    const __bf16* __restrict__ A, const __bf16* __restrict__ Bt,
    const float* __restrict__ bias, const float* __restrict__ resid,
    float* __restrict__ Cout, int Ndim, int Kdim) {
  __shared__ __align__(16) __bf16 As[128 * 64];
  __shared__ __align__(16) __bf16 Bs[64 * 64];
  int p = blockIdx.y * gridDim.x + blockIdx.x;  // nwg=512=8*64
  int l = (p & 7) * 64 + (p >> 3);              // T1 XCD swizzle
  const int m0 = (l >> 4) * 128, n0 = (l & 15) * 64;
  const int t = threadIdx.x, lane = t & 63, w = t >> 6;
  const int quad = lane >> 4, l15 = lane & 15;
  const int wr = w >> 1, wc = w & 1;
  const int srow = lane >> 3, scol8 = ((lane & 7) ^ (lane >> 3)) * 8;
  const __bf16* aS0 = A + (size_t)(m0 + w * 32 + srow) * Kdim + scol8;
  const __bf16* bS0 = Bt + (size_t)(n0 + w * 16 + srow) * Kdim + scol8;
  __bf16* lA0 = &As[(w * 32) * 64];
  __bf16* lB0 = &Bs[(w * 16) * 64];

  f32x4 acc[4][2] = {};
  for (int k0 = 0; k0 < Kdim; k0 += 64) {
    __syncthreads();
#pragma unroll
    for (int c = 0; c < 4; c++)
      glds16(aS0 + (size_t)c * 8 * Kdim + k0, lA0 + c * 8 * 64);
#pragma unroll
    for (int c = 0; c < 2; c++)
      glds16(bS0 + (size_t)c * 8 * Kdim + k0, lB0 + c * 8 * 64);
    __syncthreads();
#pragma unroll
    for (int kh = 0; kh < 2; kh++) {
      bf16x8 af[4], bg[2];
#pragma unroll
      for (int rt = 0; rt < 4; rt++)
        af[rt] = *(const bf16x8*)&As[swz(wr * 64 + rt * 16 + l15, kh * 32 + quad * 8)];
#pragma unroll
      for (int ct = 0; ct < 2; ct++)
        bg[ct] = *(const bf16x8*)&Bs[swz(wc * 32 + ct * 16 + l15, kh * 32 + quad * 8)];
#pragma unroll
      for (int rt = 0; rt < 4; rt++)
#pragma unroll
        for (int ct = 0; ct < 2; ct++)
          acc[rt][ct] = mfma16(af[rt], bg[ct], acc[rt][ct]);
    }
  }
#pragma unroll
  for (int rt = 0; rt < 4; rt++) {
    int row = m0 + wr * 64 + rt * 16 + quad * 4;
#pragma unroll
    for (int ct = 0; ct < 2; ct++) {
      int col = n0 + wc * 32 + ct * 16 + l15;
      float bcol = bias[col];
#pragma unroll
      for (int i = 0; i < 4; i++) {
        size_t idx = (size_t)(row + i) * Ndim + col;
        Cout[idx] = acc[rt][ct][i] + bcol + resid[idx];
      }
    }
  }
}

// ---------------- flash attention: S^T form (R10 body, byte-exact) ---------
// Block = (b,h,x): 128 Q rows, 32 KV iters of 64 cols. K/Gk/V 64x64 tiles
// staged once per block (swizzled, conflict-free). S^T = K*Q^T so C-layout
// gives 4 consecutive m per lane: P written as 8x ds_write_b64 (pk-cvt) into
// swizzled per-wave tile, read back as b128 A-frags for PV. No online max
// (logits bounded ~62). lrow = per-lane partials, reduced at end (xor 16/32).
// Gq arrives l2-SCALED (k_l2scaleq); Gk raw.
__global__ __launch_bounds__(256, 2) void k_flash(
    const __bf16* __restrict__ Q, const __bf16* __restrict__ K,
    const __bf16* __restrict__ Vt, const __bf16* __restrict__ Gq,
    const __bf16* __restrict__ Gk, const float* __restrict__ als,
    const float* __restrict__ psc, const float* __restrict__ nsc,
    __bf16* __restrict__ Out) {
  const int o = blockIdx.x;
  const int bh = o & 63, x = o >> 6;
  const int b = bh & 3, h = bh >> 2;
  const int t = threadIdx.x, w = t >> 6, lane = t & 63;
  const int quad = lane >> 4, l15 = lane & 15;
  const int row0 = x * 128 + w * 32;
  const float LOG2E = 1.44269504089f;
  const float sc2 = __expf(als[0]) * 0.125f * LOG2E;
  const float pos2 = psc[0] * LOG2E, neg2 = nsc[0] * LOG2E;

  __shared__ __align__(16) __bf16 Ks[64 * 64];
  __shared__ __align__(16) __bf16 Gs[64 * 64];
  __shared__ __align__(16) __bf16 Vs[64 * 64];
  __shared__ __align__(16) __bf16 Ps[4][32 * 64];

  const __bf16* Qb = Q + ((size_t)(b * NN + row0)) * DB + h * DHD;
  const __bf16* Kb = K + ((size_t)b * NM) * DB + h * DHD;
  const __bf16* Vb = Vt + (size_t)(h * DHD) * (NB * NM) + (size_t)b * NM;
  const __bf16* Gqb = Gq + (size_t)(b * NN + row0) * DP;
  const __bf16* Gkb = Gk + (size_t)b * NM * DP;

  // staging: thread t covers rows r0, r0+32 at 16B chunk (swizzled dest)
  const int r0 = t >> 3, gc = (t & 7) * 8;
  const int sw0 = swz(r0, gc), sw1 = sw0 + 32 * 64;  // (r0+32)&7 == r0&7
  const int r1 = r0 + 32;

  bf16x8 qf[2][2], gqf[2][2];
#pragma unroll
  for (int rt = 0; rt < 2; rt++)
#pragma unroll
    for (int ks = 0; ks < 2; ks++) {
      qf[rt][ks] = *(const bf16x8*)(Qb + (size_t)(rt * 16 + l15) * DB + ks * 32 + quad * 8);
      gqf[rt][ks] = *(const bf16x8*)(Gqb + (size_t)(rt * 16 + l15) * DP + ks * 32 + quad * 8);
    }

  // prefetch first slab
  bf16x8 kst0 = *(const bf16x8*)(Kb + (size_t)r0 * DB + gc);
  bf16x8 kst1 = *(const bf16x8*)(Kb + (size_t)r1 * DB + gc);
  bf16x8 gst0 = *(const bf16x8*)(Gkb + (size_t)r0 * DP + gc);
  bf16x8 gst1 = *(const bf16x8*)(Gkb + (size_t)r1 * DP + gc);
  bf16x8 vst0 = *(const bf16x8*)(Vb + (size_t)r0 * (NB * NM) + gc);
  bf16x8 vst1 = *(const bf16x8*)(Vb + (size_t)r1 * (NB * NM) + gc);

  float lrowq[2] = {};
  f32x4 oacc[2][4] = {};
  f32x4 z4 = {0.f, 0.f, 0.f, 0.f};

  for (int m0 = 0; m0 < NM; m0 += 64) {
    __syncthreads();  // prior iter's tile reads complete
    *(bf16x8*)&Ks[sw0] = kst0;
    *(bf16x8*)&Ks[sw1] = kst1;
    *(bf16x8*)&Gs[sw0] = gst0;
    *(bf16x8*)&Gs[sw1] = gst1;
    *(bf16x8*)&Vs[sw0] = vst0;
    *(bf16x8*)&Vs[sw1] = vst1;
    __syncthreads();  // tiles visible
    if (m0 + 64 < NM) {  // prefetch next slab during compute
      kst0 = *(const bf16x8*)(Kb + (size_t)(m0 + 64 + r0) * DB + gc);
      kst1 = *(const bf16x8*)(Kb + (size_t)(m0 + 64 + r1) * DB + gc);
      gst0 = *(const bf16x8*)(Gkb + (size_t)(m0 + 64 + r0) * DP + gc);
      gst1 = *(const bf16x8*)(Gkb + (size_t)(m0 + 64 + r1) * DP + gc);
      vst0 = *(const bf16x8*)(Vb + (size_t)r0 * (NB * NM) + m0 + 64 + gc);
      vst1 = *(const bf16x8*)(Vb + (size_t)r1 * (NB * NM) + m0 + 64 + gc);
    }
    bf16x8 kf[4][2], gkf[4][2];
#pragma unroll
    for (int ct = 0; ct < 4; ct++)
#pragma unroll
      for (int ks = 0; ks < 2; ks++) {
        int off = swz(ct * 16 + l15, ks * 32 + quad * 8);
        kf[ct][ks] = *(const bf16x8*)&Ks[off];
        gkf[ct][ks] = *(const bf16x8*)&Gs[off];
      }
    // S^T tiles: D[m-block ct][n-block rt], A=K rows (m), B=Q rows (n).
    // C-layout: col = n = l15, row = m = quad*4+i -> 4 consecutive m/lane.
#pragma unroll
    for (int ct = 0; ct < 4; ct++)
#pragma unroll
      for (int rt = 0; rt < 2; rt++) {
        f32x4 s = mfma16(kf[ct][1], qf[rt][1], mfma16(kf[ct][0], qf[rt][0], z4));
        f32x4 bg = mfma16(gkf[ct][1], gqf[rt][1], mfma16(gkf[ct][0], gqf[rt][0], z4));
        bf16x4 pk;
        float part = 0.f;
#pragma unroll
        for (int i = 0; i < 4; i++) {
          float bb = bg[i];
          float scl = bb > 0.f ? pos2 : neg2;
          float p = __builtin_amdgcn_exp2f(fmaf(bb, scl, s[i] * sc2));
          part += p;
          pk[i] = (__bf16)p;
        }
        lrowq[rt] += part;
        *(bf16x4*)&Ps[w][swz(rt * 16 + l15, ct * 16 + quad * 4)] = pk;
      }
    // PV: A = P[n][m] (b128 from swizzled per-wave tile), B = V^T[d][m]
    bf16x8 pf[2][2], vf[4][2];
#pragma unroll
    for (int rt = 0; rt < 2; rt++)
#pragma unroll
      for (int ms = 0; ms < 2; ms++)
        pf[rt][ms] = *(const bf16x8*)&Ps[w][swz(rt * 16 + l15, ms * 32 + quad * 8)];
#pragma unroll
    for (int dt = 0; dt < 4; dt++)
#pragma unroll
      for (int ms = 0; ms < 2; ms++)
        vf[dt][ms] = *(const bf16x8*)&Vs[swz(dt * 16 + l15, ms * 32 + quad * 8)];
#pragma unroll
    for (int rt = 0; rt < 2; rt++)
#pragma unroll
      for (int dt = 0; dt < 4; dt++) {
        oacc[rt][dt] = mfma16(pf[rt][0], vf[dt][0], oacc[rt][dt]);
        oacc[rt][dt] = mfma16(pf[rt][1], vf[dt][1], oacc[rt][dt]);
      }
  }
  // lrowq[rt] holds this lane's quad-share for n = rt*16+l15: sum over quads,
  // then redistribute to the oacc layout (n = rt*16+quad*4+i) via shuffles.
  float ltot[2];
#pragma unroll
  for (int rt = 0; rt < 2; rt++) {
    float l = lrowq[rt];
    l += __shfl_xor(l, 16, 64);
    l += __shfl_xor(l, 32, 64);
    ltot[rt] = l;
  }
#pragma unroll
  for (int rt = 0; rt < 2; rt++)
#pragma unroll
    for (int i = 0; i < 4; i++) {
      float li = __shfl(ltot[rt], quad * 4 + i, 64);
      float inv = 1.f / li;
#pragma unroll
      for (int dt = 0; dt < 4; dt++)
        Out[(size_t)(b * NN + row0 + rt * 16 + quad * 4 + i) * DB + h * DHD + dt * 16 + l15] =
            (__bf16)(oacc[rt][dt][i] * inv);
    }
}

// ---------------------------------------------------------------------------
extern "C" void kernel_launch(void* const* d_in, const int* in_sizes, int n_in,
                              void* d_out, int out_size, void* d_ws, size_t ws_size,
                              hipStream_t stream) {
  const float* dataset = (const float*)d_in[0];
  const float* visual = (const float*)d_in[1];
  const float* wq_w = (const float*)d_in[2];
  const float* wq_b = (const float*)d_in[3];
  const float* wk_w = (const float*)d_in[4];
  const float* wk_b = (const float*)d_in[5];
  const float* wv_w = (const float*)d_in[6];
  const float* wv_b = (const float*)d_in[7];
  const float* wo_w = (const float*)d_in[8];
  const float* wo_b = (const float*)d_in[9];
  const float* gq_w = (const float*)d_in[10];
  const float* gq_b = (const float*)d_in[11];
  const float* gk_w = (const float*)d_in[12];
  const float* gk_b = (const float*)d_in[13];
  const float* pos_scale = (const float*)d_in[14];
  const float* neg_scale = (const float*)d_in[15];
  const float* als = (const float*)d_in[16];
  const float* ln_q_g = (const float*)d_in[17];
  const float* ln_q_b = (const float*)d_in[18];
  const float* ln_kv_g = (const float*)d_in[19];
  const float* ln_kv_b = (const float*)d_in[20];
  const float* ln_out_g = (const float*)d_in[21];
  const float* ln_out_b = (const float*)d_in[22];
  const float* ff1_w = (const float*)d_in[23];
  const float* ff1_b = (const float*)d_in[24];
  const float* ff2_w = (const float*)d_in[25];
  const float* ff2_b = (const float*)d_in[26];

  char* ws = (char*)d_ws;
  size_t off = 0;
  auto alloc = [&](size_t bytes) {
    size_t o = off;
    off += (bytes + 255) & ~(size_t)255;
    return o;
  };
  __bf16* t_wq = (__bf16*)(ws + alloc((size_t)1024 * 1024 * 2));
  __bf16* t_wk = (__bf16*)(ws + alloc((size_t)1024 * 1024 * 2));
  __bf16* t_wv = (__bf16*)(ws + alloc((size_t)1024 * 1024 * 2));
  __bf16* t_wo = (__bf16*)(ws + alloc((size_t)1024 * 1024 * 2));
  __bf16* t_ff1 = (__bf16*)(ws + alloc((size_t)2048 * 1024 * 2));
  __bf16* t_ff2 = (__bf16*)(ws + alloc((size_t)1024 * 2048 * 2));
  __bf16* t_gq = (__bf16*)(ws + alloc((size_t)64 * 1024 * 2));
  __bf16* t_gk = (__bf16*)(ws + alloc((size_t)64 * 1024 * 2));
  size_t qin_off = alloc((size_t)4096 * 1024 * 2);   // aliased as hbuf later
  size_t kvin_off = alloc((size_t)8192 * 1024 * 2);  // aliased as out1(f32) later
  __bf16* qin = (__bf16*)(ws + qin_off);
  __bf16* kvin = (__bf16*)(ws + kvin_off);
  __bf16* geoq = (__bf16*)(ws + alloc((size_t)4096 * 64 * 2));
  __bf16* geok = (__bf16*)(ws + alloc((size_t)8192 * 64 * 2));
  float* sums = (float*)(ws + alloc((size_t)2 * 4 * 64 * 4));
  __bf16* qb = (__bf16*)(ws + alloc((size_t)4096 * 1024 * 2));
  __bf16* kb = (__bf16*)(ws + alloc((size_t)8192 * 1024 * 2));
  __bf16* vtb = (__bf16*)(ws + alloc((size_t)1024 * 8192 * 2));  // V^T [ch][tok]
  __bf16* attn = (__bf16*)(ws + alloc((size_t)4096 * 1024 * 2));
  __bf16* ffh = (__bf16*)(ws + alloc((size_t)4096 * 2048 * 2));
  // aliases (lifetimes disjoint):
  float* out1 = (float*)(ws + kvin_off);   // f32 [4096,1024] over kv_in
  __bf16* hbuf = (__bf16*)(ws + qin_off);  // bf16 [4096,1024] over q_in
  float* outp = (float*)d_out;

  dim3 blk(256);
  // 1. all weight transposes in one launch
  k_transpose_all<<<8320, blk, 0, stream>>>(wq_w, wk_w, wv_w, wo_w, ff1_w, ff2_w,
                                            gq_w, gk_w, t_wq, t_wk, t_wv, t_wo,
                                            t_ff1, t_ff2, t_gq, t_gk);
  // 2. both input layernorms in one launch
  k_layernorm2<<<12288, blk, 0, stream>>>(dataset, ln_q_g, ln_q_b, qin,
                                          visual, ln_kv_g, ln_kv_b, kvin);
  // 3. geo path (l2sum fused into geo epilogue)
  hipMemsetAsync(sums, 0, 2 * 4 * 64 * 4, stream);
  k_geo<<<384, blk, 0, stream>>>(qin, kvin, t_gq, t_gk, gq_b, gk_b, geoq, geok,
                                 sums);
  k_l2scaleq<<<dim3(8, 4), blk, 0, stream>>>(geoq, sums);
  // 4. fused QKV projections (XCD-swizzled, BK=64 swizzled LDS)
  k_qkv<<<1280, blk, 0, stream>>>(qin, kvin, t_wq, t_wk, t_wv,
                                  wq_b, wk_b, wv_b, qb, kb, vtb);
  // 5. flash attention (bias fused, S^T form, R10 body)
  k_flash<<<512, blk, 0, stream>>>(qb, kb, vtb, geoq, geok, als,
                                   pos_scale, neg_scale, attn);
  // 6. output projection + residual, LN, FFN (XCD-swizzled, BK=64 swz LDS)
  k_gemmn64<<<dim3(16, 32), blk, 0, stream>>>(attn, t_wo, wo_b, dataset, out1,
                                              1024, 1024);
  k_layernorm<<<4096, blk, 0, stream>>>(out1, ln_out_g, ln_out_b, hbuf);
  k_gemm128g<<<dim3(16, 32), blk, 0, stream>>>(hbuf, t_ff1, ff1_b, ffh,
                                               2048, 1024);
  k_gemmn64<<<dim3(16, 32), blk, 0, stream>>>(ffh, t_ff2, ff2_b, out1, outp,
                                              1024, 2048);
}

// Round 13
// 410.793 us; speedup vs baseline: 1.0553x; 1.0192x over previous
//
#include <hip/hip_runtime.h>

// ---------------------------------------------------------------------------
// BiasCrossAttentionFusion on gfx950 — round 19.
//   R19 vs R18 (418.7us best): config locked; last lever that touches no
//   proven-fragile kernel body is dispatch-boundary elimination:
//   (1) k_transpose_all (8320 blk) + k_layernorm2 (12288 blk) merged into
//       one k_pre launch (disjoint in/out streamers; tail/head overlap),
//   (2) sums memset folded into k_pre block 0 (kills a 2KB dispatch),
//   (3) k_l2scaleq (32 blocks! serial between geo and qkv) folded into the
//       qkv launch as ids 1280..1311 (nwg 1312=8*164 stays bijective; qkv
//       never touches geoq/sums; flash ordering preserved by stream).
//   All hot-loop bodies byte-identical to R18.
// ---------------------------------------------------------------------------

typedef __bf16 bf16x8 __attribute__((ext_vector_type(8)));
typedef __bf16 bf16x4 __attribute__((ext_vector_type(4)));
typedef float  f32x4  __attribute__((ext_vector_type(4)));

__device__ inline f32x4 mfma16(bf16x8 a, bf16x8 b, f32x4 c) {
  return __builtin_amdgcn_mfma_f32_16x16x32_bf16(a, b, c, 0, 0, 0);
}

__device__ inline void glds16(const void* g, void* l) {
  __builtin_amdgcn_global_load_lds(
      (const __attribute__((address_space(1))) void*)g,
      (__attribute__((address_space(3))) void*)l, 16, 0, 0);
}

// swizzled LDS offset for a 64-elem bf16 row: 16B-chunk index XOR (row&7)
__device__ inline int swz(int row, int col) {
  return row * 64 + ((((col >> 3) ^ (row & 7)) << 3) | (col & 7));
}

#define DB 1024
#define DH 16
#define DHD 64
#define DP 64
#define NB 4
#define NN 1024
#define NM 2048

// ---------------- LayerNorm D=1024 body, bf16 out --------------------------
__device__ inline void ln_body(const float* __restrict__ x,
                               const float* __restrict__ g,
                               const float* __restrict__ bb,
                               __bf16* __restrict__ y, size_t row) {
  int t = threadIdx.x;
  float4 v = ((const float4*)(x + row * 1024))[t];
  float s = v.x + v.y + v.z + v.w;
  float ss = v.x * v.x + v.y * v.y + v.z * v.z + v.w * v.w;
#pragma unroll
  for (int o = 32; o; o >>= 1) {
    s += __shfl_down(s, o, 64);
    ss += __shfl_down(ss, o, 64);
  }
  __shared__ float r1[4], r2[4];
  if ((t & 63) == 0) { r1[t >> 6] = s; r2[t >> 6] = ss; }
  __syncthreads();
  s = r1[0] + r1[1] + r1[2] + r1[3];
  ss = r2[0] + r2[1] + r2[2] + r2[3];
  float mu = s * (1.f / 1024.f);
  float rstd = rsqrtf(ss * (1.f / 1024.f) - mu * mu + 1e-5f);
  float4 gv = ((const float4*)g)[t];
  float4 bv = ((const float4*)bb)[t];
  __bf16* yr = y + row * 1024 + t * 4;
  yr[0] = (__bf16)((v.x - mu) * rstd * gv.x + bv.x);
  yr[1] = (__bf16)((v.y - mu) * rstd * gv.y + bv.y);
  yr[2] = (__bf16)((v.z - mu) * rstd * gv.z + bv.z);
  yr[3] = (__bf16)((v.w - mu) * rstd * gv.w + bv.w);
}

// ---------------- merged pre-pass: transposes + input LNs + sums zero ------
// ids [0,8320): weight transposes (f32 [K,O] -> bf16 [O,K])
// ids [8320,20608): layernorm rows (4096 q + 8192 kv)
// block 0 additionally zeroes sums (completes before k_geo by stream order)
__global__ __launch_bounds__(256) void k_pre(
    const float* __restrict__ w0, const float* __restrict__ w1,
    const float* __restrict__ w2, const float* __restrict__ w3,
    const float* __restrict__ f1, const float* __restrict__ f2,
    const float* __restrict__ g0, const float* __restrict__ g1,
    __bf16* __restrict__ o0, __bf16* __restrict__ o1,
    __bf16* __restrict__ o2, __bf16* __restrict__ o3,
    __bf16* __restrict__ of1, __bf16* __restrict__ of2,
    __bf16* __restrict__ og0, __bf16* __restrict__ og1,
    const float* __restrict__ x1, const float* __restrict__ lg1,
    const float* __restrict__ lb1, __bf16* __restrict__ y1,
    const float* __restrict__ x2, const float* __restrict__ lg2,
    const float* __restrict__ lb2, __bf16* __restrict__ y2,
    float* __restrict__ sums) {
  int id = blockIdx.x;
  if (id >= 8320) {
    int row = id - 8320;
    if (row < 4096) ln_body(x1, lg1, lb1, y1, row);
    else ln_body(x2, lg2, lb2, y2, row - 4096);
    return;
  }
  if (id == 0) {  // zero sums[512]
    sums[threadIdx.x] = 0.f;
    sums[threadIdx.x + 256] = 0.f;
  }
  __shared__ float tile[32][33];
  const float* in;
  __bf16* out;
  int K, O, x, y;
  if (id < 4096) {
    int mi = id >> 10, r = id & 1023;
    in = mi == 0 ? w0 : mi == 1 ? w1 : mi == 2 ? w2 : w3;
    out = mi == 0 ? o0 : mi == 1 ? o1 : mi == 2 ? o2 : o3;
    K = 1024; O = 1024; x = r & 31; y = r >> 5;
  } else if (id < 6144) {
    int r = id - 4096; in = f1; out = of1; K = 1024; O = 2048; x = r & 63; y = r >> 6;
  } else if (id < 8192) {
    int r = id - 6144; in = f2; out = of2; K = 2048; O = 1024; x = r & 31; y = r >> 5;
  } else if (id < 8256) {
    int r = id - 8192; in = g0; out = og0; K = 1024; O = 64; x = r & 1; y = r >> 1;
  } else {
    int r = id - 8256; in = g1; out = og1; K = 1024; O = 64; x = r & 1; y = r >> 1;
  }
  int k0 = y * 32, o0c = x * 32;
  int tx = threadIdx.x & 31, ty = threadIdx.x >> 5;
#pragma unroll
  for (int r = ty; r < 32; r += 8)
    tile[r][tx] = in[(size_t)(k0 + r) * O + (o0c + tx)];
  __syncthreads();
#pragma unroll
  for (int r = ty; r < 32; r += 8)
    out[(size_t)(o0c + r) * K + (k0 + tx)] = (__bf16)tile[tx][r];
}

// ---------------- output LayerNorm (one block/row) -------------------------
__global__ __launch_bounds__(256) void k_layernorm(
    const float* __restrict__ x, const float* __restrict__ g,
    const float* __restrict__ bb, __bf16* __restrict__ y) {
  ln_body(x, g, bb, y, blockIdx.x);
}

// ---------------- geo projections + FUSED l2 column sum-of-squares ---------
__global__ __launch_bounds__(256) void k_geo(
    const __bf16* __restrict__ qin, const __bf16* __restrict__ kvin,
    const __bf16* __restrict__ gqw, const __bf16* __restrict__ gkw,
    const float* __restrict__ gqb, const float* __restrict__ gkb,
    __bf16* __restrict__ geoq, __bf16* __restrict__ geok,
    float* __restrict__ sums) {
  const int blk = blockIdx.x;
  const bool isq = blk < 128;
  const __bf16* A = isq ? qin : kvin;
  const __bf16* Bt = isq ? gqw : gkw;
  const float* bias = isq ? gqb : gkb;
  __bf16* C = isq ? geoq : geok;
  const int row0 = (isq ? blk : blk - 128) * 32;
  __shared__ __align__(16) __bf16 As[32][72], Bs[64][72];
  __shared__ float ls[64];
  const int t = threadIdx.x, lane = t & 63, w = t >> 6;
  const int quad = lane >> 4, l15 = lane & 15;
  const int wr = w >> 1, wc = w & 1;
  const int sr = t >> 3, skc = (t & 7) * 8;
  const __bf16* aP = A + (size_t)(row0 + sr) * 1024 + skc;
  const __bf16* bP0 = Bt + (size_t)sr * 1024 + skc;
  const __bf16* bP1 = Bt + (size_t)(sr + 32) * 1024 + skc;
  bf16x8 av = *(const bf16x8*)aP;
  bf16x8 bv0 = *(const bf16x8*)bP0;
  bf16x8 bv1 = *(const bf16x8*)bP1;
  f32x4 acc[2] = {};
  for (int k0 = 0; k0 < 1024; k0 += 64) {
    __syncthreads();
    *(bf16x8*)&As[sr][skc] = av;
    *(bf16x8*)&Bs[sr][skc] = bv0;
    *(bf16x8*)&Bs[sr + 32][skc] = bv1;
    __syncthreads();
    if (k0 + 64 < 1024) {
      av = *(const bf16x8*)(aP + k0 + 64);
      bv0 = *(const bf16x8*)(bP0 + k0 + 64);
      bv1 = *(const bf16x8*)(bP1 + k0 + 64);
    }
#pragma unroll
    for (int ks = 0; ks < 2; ks++) {
      bf16x8 af = *(const bf16x8*)&As[wr * 16 + l15][ks * 32 + quad * 8];
#pragma unroll
      for (int ct = 0; ct < 2; ct++) {
        bf16x8 bfr = *(const bf16x8*)&Bs[wc * 32 + ct * 16 + l15][ks * 32 + quad * 8];
        acc[ct] = mfma16(af, bfr, acc[ct]);
      }
    }
  }
  if (t < 64) ls[t] = 0.f;
  __syncthreads();
  float sq[2] = {0.f, 0.f};
#pragma unroll
  for (int ct = 0; ct < 2; ct++) {
    int col = wc * 32 + ct * 16 + l15;
    float bc = bias[col];
#pragma unroll
    for (int i = 0; i < 4; i++) {
      int row = row0 + wr * 16 + quad * 4 + i;
      __bf16 hv = (__bf16)(acc[ct][i] + bc);
      C[(size_t)row * 64 + col] = hv;
      float fv = (float)hv;
      sq[ct] += fv * fv;
    }
  }
#pragma unroll
  for (int ct = 0; ct < 2; ct++)
    atomicAdd(&ls[wc * 32 + ct * 16 + l15], sq[ct]);
  __syncthreads();
  if (t < 64) {
    int z = isq ? 0 : 1;
    int b = isq ? (row0 >> 10) : (row0 >> 11);
    atomicAdd(&sums[z * 256 + b * 64 + t], ls[t]);
  }
}

// ---------------- fused QKV + l2scaleq: 1312 blocks ------------------------
// ids [0,1280): qb(256) + kb(512) + vtb(512) GEMM blocks (T1 XCD swizzle,
// BK=64, swizzled LDS). ids [1280,1312): scale geoq by 1/(||q||*||k||)
// (32 light blocks overlapped under the GEMM; flash ordering via stream).
__global__ __launch_bounds__(256, 3) void k_qkv(
    const __bf16* __restrict__ qin, const __bf16* __restrict__ kvin,
    const __bf16* __restrict__ twq, const __bf16* __restrict__ twk,
    const __bf16* __restrict__ twv, const float* __restrict__ qbias,
    const float* __restrict__ kbias, const float* __restrict__ vbias,
    __bf16* __restrict__ qb, __bf16* __restrict__ kb, __bf16* __restrict__ vtb,
    __bf16* __restrict__ geoq, const float* __restrict__ sums) {
  int id0 = blockIdx.x;
  int id = (id0 & 7) * 164 + (id0 >> 3);  // nwg=1312=8*164, bijective
  if (id >= 1280) {  // l2scaleq part: 32 blocks
    int r = id - 1280;
    int chunk = r & 7, b = r >> 3;
    unsigned* base = (unsigned*)(geoq + (size_t)b * 1024 * 64) + chunk * 128 * 32;
    int t = threadIdx.x, c = t & 31, ro = t >> 5;
    float sq0 = sums[b * 64 + c * 2], sq1 = sums[b * 64 + c * 2 + 1];
    float sk0 = sums[256 + b * 64 + c * 2], sk1 = sums[256 + b * 64 + c * 2 + 1];
    float m0 = 1.f / (fmaxf(sqrtf(sq0), 1e-12f) * fmaxf(sqrtf(sk0), 1e-12f));
    float m1 = 1.f / (fmaxf(sqrtf(sq1), 1e-12f) * fmaxf(sqrtf(sk1), 1e-12f));
    for (int r2 = ro; r2 < 128; r2 += 8) {
      unsigned u = base[r2 * 32 + c];
      float f0 = __uint_as_float(u << 16) * m0;
      float f1 = __uint_as_float(u & 0xffff0000u) * m1;
      unsigned short h0 = __builtin_bit_cast(unsigned short, (__bf16)f0);
      unsigned short h1 = __builtin_bit_cast(unsigned short, (__bf16)f1);
      base[r2 * 32 + c] = (unsigned)h0 | ((unsigned)h1 << 16);
    }
    return;
  }
  const __bf16 *A, *Bt;
  const float* bias;
  __bf16* C;
  int my, nx, Ndim;
  bool rowbias;
  if (id < 256) {
    A = qin; Bt = twq; bias = qbias; C = qb;
    nx = id & 7; my = id >> 3; Ndim = 1024; rowbias = false;
  } else if (id < 768) {
    id -= 256;
    A = kvin; Bt = twk; bias = kbias; C = kb;
    nx = id & 7; my = id >> 3; Ndim = 1024; rowbias = false;
  } else {
    id -= 768;
    A = twv; Bt = kvin; bias = vbias; C = vtb;
    nx = id & 63; my = id >> 6; Ndim = 8192; rowbias = true;
  }
  const int Kdim = 1024;
  __shared__ __align__(16) __bf16 As[128 * 64];
  __shared__ __align__(16) __bf16 Bs[128 * 64];
  const int m0 = my * 128, n0 = nx * 128;
  const int t = threadIdx.x, lane = t & 63, w = t >> 6;
  const int quad = lane >> 4, l15 = lane & 15;
  const int wr = w >> 1, wc = w & 1;
  const int srow = lane >> 3, scol8 = ((lane & 7) ^ (lane >> 3)) * 8;
  const __bf16* aS0 = A + (size_t)(m0 + w * 32 + srow) * Kdim + scol8;
  const __bf16* bS0 = Bt + (size_t)(n0 + w * 32 + srow) * Kdim + scol8;
  __bf16* lA0 = &As[(w * 32) * 64];
  __bf16* lB0 = &Bs[(w * 32) * 64];

  f32x4 acc[4][4] = {};
  for (int k0 = 0; k0 < Kdim; k0 += 64) {
    __syncthreads();
#pragma unroll
    for (int c = 0; c < 4; c++) {
      glds16(aS0 + (size_t)c * 8 * Kdim + k0, lA0 + c * 8 * 64);
      glds16(bS0 + (size_t)c * 8 * Kdim + k0, lB0 + c * 8 * 64);
    }
    __syncthreads();
#pragma unroll
    for (int kh = 0; kh < 2; kh++) {
      bf16x8 af[4], bg[4];
#pragma unroll
      for (int rt = 0; rt < 4; rt++)
        af[rt] = *(const bf16x8*)&As[swz(wr * 64 + rt * 16 + l15, kh * 32 + quad * 8)];
#pragma unroll
      for (int ct = 0; ct < 4; ct++)
        bg[ct] = *(const bf16x8*)&Bs[swz(wc * 64 + ct * 16 + l15, kh * 32 + quad * 8)];
#pragma unroll
      for (int rt = 0; rt < 4; rt++)
#pragma unroll
        for (int ct = 0; ct < 4; ct++)
          acc[rt][ct] = mfma16(af[rt], bg[ct], acc[rt][ct]);
    }
  }
#pragma unroll
  for (int rt = 0; rt < 4; rt++) {
    int row = m0 + wr * 64 + rt * 16 + quad * 4;
#pragma unroll
    for (int ct = 0; ct < 4; ct++) {
      int col = n0 + wc * 64 + ct * 16 + l15;
      float bcol = rowbias ? 0.f : bias[col];
#pragma unroll
      for (int i = 0; i < 4; i++) {
        float vv = acc[rt][ct][i] + (rowbias ? bias[row + i] : bcol);
        C[(size_t)(row + i) * Ndim + col] = (__bf16)vv;
      }
    }
  }
}

// ---------------- big GEMM 128x128 (ff1: gelu epilogue) --------------------
__global__ __launch_bounds__(256, 3) void k_gemm128g(
    const __bf16* __restrict__ A, const __bf16* __restrict__ Bt,
    const float* __restrict__ bias, __bf16* __restrict__ Cout,
    int Ndim, int Kdim) {
  __shared__ __align__(16) __bf16 As[128 * 64];
  __shared__ __align__(16) __bf16 Bs[128 * 64];
  int p = blockIdx.y * gridDim.x + blockIdx.x;  // nwg=512=8*64
  int l = (p & 7) * 64 + (p >> 3);              // T1 XCD swizzle
  const int m0 = (l >> 4) * 128, n0 = (l & 15) * 128;
  const int t = threadIdx.x, lane = t & 63, w = t >> 6;
  const int quad = lane >> 4, l15 = lane & 15;
  const int wr = w >> 1, wc = w & 1;
  const int srow = lane >> 3, scol8 = ((lane & 7) ^ (lane >> 3)) * 8;
  const __bf16* aS0 = A + (size_t)(m0 + w * 32 + srow) * Kdim + scol8;
  const __bf16* bS0 = Bt + (size_t)(n0 + w * 32 + srow) * Kdim + scol8;
  __bf16* lA0 = &As[(w * 32) * 64];
  __bf16* lB0 = &Bs[(w * 32) * 64];

  f32x4 acc[4][4] = {};
  for (int k0 = 0; k0 < Kdim; k0 += 64) {
    __syncthreads();
#pragma unroll
    for (int c = 0; c < 4; c++) {
      glds16(aS0 + (size_t)c * 8 * Kdim + k0, lA0 + c * 8 * 64);
      glds16(bS0 + (size_t)c * 8 * Kdim + k0, lB0 + c * 8 * 64);
    }
    __syncthreads();
#pragma unroll
    for (int kh = 0; kh < 2; kh++) {
      bf16x8 af[4], bg[4];
#pragma unroll
      for (int rt = 0; rt < 4; rt++)
        af[rt] = *(const bf16x8*)&As[swz(wr * 64 + rt * 16 + l15, kh * 32 + quad * 8)];
#pragma unroll
      for (int ct = 0; ct < 4; ct++)
        bg[ct] = *(const bf16x8*)&Bs[swz(wc * 64 + ct * 16 + l15, kh * 32 + quad * 8)];
#pragma unroll
      for (int rt = 0; rt < 4; rt++)
#pragma unroll
        for (int ct = 0; ct < 4; ct++)
          acc[rt][ct] = mfma16(af[rt], bg[ct], acc[rt][ct]);
    }
  }
#pragma unroll
  for (int rt = 0; rt < 4; rt++) {
    int row = m0 + wr * 64 + rt * 16 + quad * 4;
#pragma unroll
    for (int ct = 0; ct < 4; ct++) {
      int col = n0 + wc * 64 + ct * 16 + l15;
      float bcol = bias[col];
#pragma unroll
      for (int i = 0; i < 4; i++) {
        float vv = acc[rt][ct][i] + bcol;
        Cout[(size_t)(row + i) * Ndim + col] =
            (__bf16)(0.5f * vv * (1.f + erff(vv * 0.70710678118f)));
      }
    }
  }
}

// ---------------- GEMM 128x64 tile (wo / ff2): +bias +resid -> f32 ---------
__global__ __launch_bounds__(256, 3) void k_gemmn64(
    const __bf16* __restrict__ A, const __bf16* __restrict__ Bt,
    const float* __restrict__ bias, const float* __restrict__ resid,
    float* __restrict__ Cout, int Ndim, int Kdim) {
  __shared__ __align__(16) __bf16 As[128 * 64];
  __shared__ __align__(16) __bf16 Bs[64 * 64];
  int p = blockIdx.y * gridDim.x + blockIdx.x;  // nwg=512=8*64
  int l = (p & 7) * 64 + (p >> 3);              // T1 XCD swizzle
  const int m0 = (l >> 4) * 128, n0 = (l & 15) * 64;
  const int t = threadIdx.x, lane = t & 63, w = t >> 6;
  const int quad = lane >> 4, l15 = lane & 15;
  const int wr = w >> 1, wc = w & 1;
  const int srow = lane >> 3, scol8 = ((lane & 7) ^ (lane >> 3)) * 8;
  const __bf16* aS0 = A + (size_t)(m0 + w * 32 + srow) * Kdim + scol8;
  const __bf16* bS0 = Bt + (size_t)(n0 + w * 16 + srow) * Kdim + scol8;
  __bf16* lA0 = &As[(w * 32) * 64];
  __bf16* lB0 = &Bs[(w * 16) * 64];

  f32x4 acc[4][2] = {};
  for (int k0 = 0; k0 < Kdim; k0 += 64) {
    __syncthreads();
#pragma unroll
    for (int c = 0; c < 4; c++)
      glds16(aS0 + (size_t)c * 8 * Kdim + k0, lA0 + c * 8 * 64);
#pragma unroll
    for (int c = 0; c < 2; c++)
      glds16(bS0 + (size_t)c * 8 * Kdim + k0, lB0 + c * 8 * 64);
    __syncthreads();
#pragma unroll
    for (int kh = 0; kh < 2; kh++) {
      bf16x8 af[4], bg[2];
#pragma unroll
      for (int rt = 0; rt < 4; rt++)
        af[rt] = *(const bf16x8*)&As[swz(wr * 64 + rt * 16 + l15, kh * 32 + quad * 8)];
#pragma unroll
      for (int ct = 0; ct < 2; ct++)
        bg[ct] = *(const bf16x8*)&Bs[swz(wc * 32 + ct * 16 + l15, kh * 32 + quad * 8)];
#pragma unroll
      for (int rt = 0; rt < 4; rt++)
#pragma unroll
        for (int ct = 0; ct < 2; ct++)
          acc[rt][ct] = mfma16(af[rt], bg[ct], acc[rt][ct]);
    }
  }
#pragma unroll
  for (int rt = 0; rt < 4; rt++) {
    int row = m0 + wr * 64 + rt * 16 + quad * 4;
#pragma unroll
    for (int ct = 0; ct < 2; ct++) {
      int col = n0 + wc * 32 + ct * 16 + l15;
      float bcol = bias[col];
#pragma unroll
      for (int i = 0; i < 4; i++) {
        size_t idx = (size_t)(row + i) * Ndim + col;
        Cout[idx] = acc[rt][ct][i] + bcol + resid[idx];
      }
    }
  }
}

// ---------------- flash attention: S^T form (R10 body, byte-exact) ---------
// Block = (b,h,x): 128 Q rows, 32 KV iters of 64 cols. K/Gk/V 64x64 tiles
// staged once per block (swizzled, conflict-free). S^T = K*Q^T so C-layout
// gives 4 consecutive m per lane: P written as 8x ds_write_b64 (pk-cvt) into
// swizzled per-wave tile, read back as b128 A-frags for PV. No online max
// (logits bounded ~62). lrow = per-lane partials, reduced at end (xor 16/32).
// Gq arrives l2-SCALED; Gk raw.
__global__ __launch_bounds__(256, 2) void k_flash(
    const __bf16* __restrict__ Q, const __bf16* __restrict__ K,
    const __bf16* __restrict__ Vt, const __bf16* __restrict__ Gq,
    const __bf16* __restrict__ Gk, const float* __restrict__ als,
    const float* __restrict__ psc, const float* __restrict__ nsc,
    __bf16* __restrict__ Out) {
  const int o = blockIdx.x;
  const int bh = o & 63, x = o >> 6;
  const int b = bh & 3, h = bh >> 2;
  const int t = threadIdx.x, w = t >> 6, lane = t & 63;
  const int quad = lane >> 4, l15 = lane & 15;
  const int row0 = x * 128 + w * 32;
  const float LOG2E = 1.44269504089f;
  const float sc2 = __expf(als[0]) * 0.125f * LOG2E;
  const float pos2 = psc[0] * LOG2E, neg2 = nsc[0] * LOG2E;

  __shared__ __align__(16) __bf16 Ks[64 * 64];
  __shared__ __align__(16) __bf16 Gs[64 * 64];
  __shared__ __align__(16) __bf16 Vs[64 * 64];
  __shared__ __align__(16) __bf16 Ps[4][32 * 64];

  const __bf16* Qb = Q + ((size_t)(b * NN + row0)) * DB + h * DHD;
  const __bf16* Kb = K + ((size_t)b * NM) * DB + h * DHD;
  const __bf16* Vb = Vt + (size_t)(h * DHD) * (NB * NM) + (size_t)b * NM;
  const __bf16* Gqb = Gq + (size_t)(b * NN + row0) * DP;
  const __bf16* Gkb = Gk + (size_t)b * NM * DP;

  // staging: thread t covers rows r0, r0+32 at 16B chunk (swizzled dest)
  const int r0 = t >> 3, gc = (t & 7) * 8;
  const int sw0 = swz(r0, gc), sw1 = sw0 + 32 * 64;  // (r0+32)&7 == r0&7
  const int r1 = r0 + 32;

  bf16x8 qf[2][2], gqf[2][2];
#pragma unroll
  for (int rt = 0; rt < 2; rt++)
#pragma unroll
    for (int ks = 0; ks < 2; ks++) {
      qf[rt][ks] = *(const bf16x8*)(Qb + (size_t)(rt * 16 + l15) * DB + ks * 32 + quad * 8);
      gqf[rt][ks] = *(const bf16x8*)(Gqb + (size_t)(rt * 16 + l15) * DP + ks * 32 + quad * 8);
    }

  // prefetch first slab
  bf16x8 kst0 = *(const bf16x8*)(Kb + (size_t)r0 * DB + gc);
  bf16x8 kst1 = *(const bf16x8*)(Kb + (size_t)r1 * DB + gc);
  bf16x8 gst0 = *(const bf16x8*)(Gkb + (size_t)r0 * DP + gc);
  bf16x8 gst1 = *(const bf16x8*)(Gkb + (size_t)r1 * DP + gc);
  bf16x8 vst0 = *(const bf16x8*)(Vb + (size_t)r0 * (NB * NM) + gc);
  bf16x8 vst1 = *(const bf16x8*)(Vb + (size_t)r1 * (NB * NM) + gc);

  float lrowq[2] = {};
  f32x4 oacc[2][4] = {};
  f32x4 z4 = {0.f, 0.f, 0.f, 0.f};

  for (int m0 = 0; m0 < NM; m0 += 64) {
    __syncthreads();  // prior iter's tile reads complete
    *(bf16x8*)&Ks[sw0] = kst0;
    *(bf16x8*)&Ks[sw1] = kst1;
    *(bf16x8*)&Gs[sw0] = gst0;
    *(bf16x8*)&Gs[sw1] = gst1;
    *(bf16x8*)&Vs[sw0] = vst0;
    *(bf16x8*)&Vs[sw1] = vst1;
    __syncthreads();  // tiles visible
    if (m0 + 64 < NM) {  // prefetch next slab during compute
      kst0 = *(const bf16x8*)(Kb + (size_t)(m0 + 64 + r0) * DB + gc);
      kst1 = *(const bf16x8*)(Kb + (size_t)(m0 + 64 + r1) * DB + gc);
      gst0 = *(const bf16x8*)(Gkb + (size_t)(m0 + 64 + r0) * DP + gc);
      gst1 = *(const bf16x8*)(Gkb + (size_t)(m0 + 64 + r1) * DP + gc);
      vst0 = *(const bf16x8*)(Vb + (size_t)r0 * (NB * NM) + m0 + 64 + gc);
      vst1 = *(const bf16x8*)(Vb + (size_t)r1 * (NB * NM) + m0 + 64 + gc);
    }
    bf16x8 kf[4][2], gkf[4][2];
#pragma unroll
    for (int ct = 0; ct < 4; ct++)
#pragma unroll
      for (int ks = 0; ks < 2; ks++) {
        int off = swz(ct * 16 + l15, ks * 32 + quad * 8);
        kf[ct][ks] = *(const bf16x8*)&Ks[off];
        gkf[ct][ks] = *(const bf16x8*)&Gs[off];
      }
    // S^T tiles: D[m-block ct][n-block rt], A=K rows (m), B=Q rows (n).
    // C-layout: col = n = l15, row = m = quad*4+i -> 4 consecutive m/lane.
#pragma unroll
    for (int ct = 0; ct < 4; ct++)
#pragma unroll
      for (int rt = 0; rt < 2; rt++) {
        f32x4 s = mfma16(kf[ct][1], qf[rt][1], mfma16(kf[ct][0], qf[rt][0], z4));
        f32x4 bg = mfma16(gkf[ct][1], gqf[rt][1], mfma16(gkf[ct][0], gqf[rt][0], z4));
        bf16x4 pk;
        float part = 0.f;
#pragma unroll
        for (int i = 0; i < 4; i++) {
          float bb = bg[i];
          float scl = bb > 0.f ? pos2 : neg2;
          float p = __builtin_amdgcn_exp2f(fmaf(bb, scl, s[i] * sc2));
          part += p;
          pk[i] = (__bf16)p;
        }
        lrowq[rt] += part;
        *(bf16x4*)&Ps[w][swz(rt * 16 + l15, ct * 16 + quad * 4)] = pk;
      }
    // PV: A = P[n][m] (b128 from swizzled per-wave tile), B = V^T[d][m]
    bf16x8 pf[2][2], vf[4][2];
#pragma unroll
    for (int rt = 0; rt < 2; rt++)
#pragma unroll
      for (int ms = 0; ms < 2; ms++)
        pf[rt][ms] = *(const bf16x8*)&Ps[w][swz(rt * 16 + l15, ms * 32 + quad * 8)];
#pragma unroll
    for (int dt = 0; dt < 4; dt++)
#pragma unroll
      for (int ms = 0; ms < 2; ms++)
        vf[dt][ms] = *(const bf16x8*)&Vs[swz(dt * 16 + l15, ms * 32 + quad * 8)];
#pragma unroll
    for (int rt = 0; rt < 2; rt++)
#pragma unroll
      for (int dt = 0; dt < 4; dt++) {
        oacc[rt][dt] = mfma16(pf[rt][0], vf[dt][0], oacc[rt][dt]);
        oacc[rt][dt] = mfma16(pf[rt][1], vf[dt][1], oacc[rt][dt]);
      }
  }
  // lrowq[rt] holds this lane's quad-share for n = rt*16+l15: sum over quads,
  // then redistribute to the oacc layout (n = rt*16+quad*4+i) via shuffles.
  float ltot[2];
#pragma unroll
  for (int rt = 0; rt < 2; rt++) {
    float l = lrowq[rt];
    l += __shfl_xor(l, 16, 64);
    l += __shfl_xor(l, 32, 64);
    ltot[rt] = l;
  }
#pragma unroll
  for (int rt = 0; rt < 2; rt++)
#pragma unroll
    for (int i = 0; i < 4; i++) {
      float li = __shfl(ltot[rt], quad * 4 + i, 64);
      float inv = 1.f / li;
#pragma unroll
      for (int dt = 0; dt < 4; dt++)
        Out[(size_t)(b * NN + row0 + rt * 16 + quad * 4 + i) * DB + h * DHD + dt * 16 + l15] =
            (__bf16)(oacc[rt][dt][i] * inv);
    }
}

// ---------------------------------------------------------------------------
extern "C" void kernel_launch(void* const* d_in, const int* in_sizes, int n_in,
                              void* d_out, int out_size, void* d_ws, size_t ws_size,
                              hipStream_t stream) {
  const float* dataset = (const float*)d_in[0];
  const float* visual = (const float*)d_in[1];
  const float* wq_w = (const float*)d_in[2];
  const float* wq_b = (const float*)d_in[3];
  const float* wk_w = (const float*)d_in[4];
  const float* wk_b = (const float*)d_in[5];
  const float* wv_w = (const float*)d_in[6];
  const float* wv_b = (const float*)d_in[7];
  const float* wo_w = (const float*)d_in[8];
  const float* wo_b = (const float*)d_in[9];
  const float* gq_w = (const float*)d_in[10];
  const float* gq_b = (const float*)d_in[11];
  const float* gk_w = (const float*)d_in[12];
  const float* gk_b = (const float*)d_in[13];
  const float* pos_scale = (const float*)d_in[14];
  const float* neg_scale = (const float*)d_in[15];
  const float* als = (const float*)d_in[16];
  const float* ln_q_g = (const float*)d_in[17];
  const float* ln_q_b = (const float*)d_in[18];
  const float* ln_kv_g = (const float*)d_in[19];
  const float* ln_kv_b = (const float*)d_in[20];
  const float* ln_out_g = (const float*)d_in[21];
  const float* ln_out_b = (const float*)d_in[22];
  const float* ff1_w = (const float*)d_in[23];
  const float* ff1_b = (const float*)d_in[24];
  const float* ff2_w = (const float*)d_in[25];
  const float* ff2_b = (const float*)d_in[26];

  char* ws = (char*)d_ws;
  size_t off = 0;
  auto alloc = [&](size_t bytes) {
    size_t o = off;
    off += (bytes + 255) & ~(size_t)255;
    return o;
  };
  __bf16* t_wq = (__bf16*)(ws + alloc((size_t)1024 * 1024 * 2));
  __bf16* t_wk = (__bf16*)(ws + alloc((size_t)1024 * 1024 * 2));
  __bf16* t_wv = (__bf16*)(ws + alloc((size_t)1024 * 1024 * 2));
  __bf16* t_wo = (__bf16*)(ws + alloc((size_t)1024 * 1024 * 2));
  __bf16* t_ff1 = (__bf16*)(ws + alloc((size_t)2048 * 1024 * 2));
  __bf16* t_ff2 = (__bf16*)(ws + alloc((size_t)1024 * 2048 * 2));
  __bf16* t_gq = (__bf16*)(ws + alloc((size_t)64 * 1024 * 2));
  __bf16* t_gk = (__bf16*)(ws + alloc((size_t)64 * 1024 * 2));
  size_t qin_off = alloc((size_t)4096 * 1024 * 2);   // aliased as hbuf later
  size_t kvin_off = alloc((size_t)8192 * 1024 * 2);  // aliased as out1(f32) later
  __bf16* qin = (__bf16*)(ws + qin_off);
  __bf16* kvin = (__bf16*)(ws + kvin_off);
  __bf16* geoq = (__bf16*)(ws + alloc((size_t)4096 * 64 * 2));
  __bf16* geok = (__bf16*)(ws + alloc((size_t)8192 * 64 * 2));
  float* sums = (float*)(ws + alloc((size_t)2 * 4 * 64 * 4));
  __bf16* qb = (__bf16*)(ws + alloc((size_t)4096 * 1024 * 2));
  __bf16* kb = (__bf16*)(ws + alloc((size_t)8192 * 1024 * 2));
  __bf16* vtb = (__bf16*)(ws + alloc((size_t)1024 * 8192 * 2));  // V^T [ch][tok]
  __bf16* attn = (__bf16*)(ws + alloc((size_t)4096 * 1024 * 2));
  __bf16* ffh = (__bf16*)(ws + alloc((size_t)4096 * 2048 * 2));
  // aliases (lifetimes disjoint):
  float* out1 = (float*)(ws + kvin_off);   // f32 [4096,1024] over kv_in
  __bf16* hbuf = (__bf16*)(ws + qin_off);  // bf16 [4096,1024] over q_in
  float* outp = (float*)d_out;

  dim3 blk(256);
  // 1. merged pre-pass: weight transposes + input LNs + sums zero
  k_pre<<<20608, blk, 0, stream>>>(wq_w, wk_w, wv_w, wo_w, ff1_w, ff2_w,
                                   gq_w, gk_w, t_wq, t_wk, t_wv, t_wo,
                                   t_ff1, t_ff2, t_gq, t_gk,
                                   dataset, ln_q_g, ln_q_b, qin,
                                   visual, ln_kv_g, ln_kv_b, kvin, sums);
  // 2. geo path (l2sum fused into geo epilogue)
  k_geo<<<384, blk, 0, stream>>>(qin, kvin, t_gq, t_gk, gq_b, gk_b, geoq, geok,
                                 sums);
  // 3. fused QKV projections + l2scaleq (32 light blocks overlapped)
  k_qkv<<<1312, blk, 0, stream>>>(qin, kvin, t_wq, t_wk, t_wv,
                                  wq_b, wk_b, wv_b, qb, kb, vtb, geoq, sums);
  // 4. flash attention (bias fused, S^T form, R10 body)
  k_flash<<<512, blk, 0, stream>>>(qb, kb, vtb, geoq, geok, als,
                                   pos_scale, neg_scale, attn);
  // 5. output projection + residual, LN, FFN (XCD-swizzled, BK=64 swz LDS)
  k_gemmn64<<<dim3(16, 32), blk, 0, stream>>>(attn, t_wo, wo_b, dataset, out1,
                                              1024, 1024);
  k_layernorm<<<4096, blk, 0, stream>>>(out1, ln_out_g, ln_out_b, hbuf);
  k_gemm128g<<<dim3(16, 32), blk, 0, stream>>>(hbuf, t_ff1, ff1_b, ffh,
                                               2048, 1024);
  k_gemmn64<<<dim3(16, 32), blk, 0, stream>>>(ffh, t_ff2, ff2_b, out1, outp,
                                              1024, 2048);
}